// Round 1
// baseline (672.185 us; speedup 1.0000x reference)
//
#include <hip/hip_runtime.h>
#include <cstdint>
#include <cstddef>

#define NN 50000
#define NE 800000
#define D 96

// ---------------- CSR build ----------------

__global__ void count_deg(const int* __restrict__ dst, int* __restrict__ deg, int ne) {
    int e = blockIdx.x * blockDim.x + threadIdx.x;
    if (e < ne) atomicAdd(&deg[dst[e]], 1);
}

__global__ void scan_deg(const int* __restrict__ deg, int* __restrict__ startv,
                         int* __restrict__ cursor, int n) {
    __shared__ int sm[1024];
    __shared__ int base;
    if (threadIdx.x == 0) base = 0;
    __syncthreads();
    for (int off = 0; off < n; off += 1024) {
        int i = off + (int)threadIdx.x;
        int v = (i < n) ? deg[i] : 0;
        sm[threadIdx.x] = v;
        __syncthreads();
        for (int s = 1; s < 1024; s <<= 1) {
            int t = (threadIdx.x >= (unsigned)s) ? sm[threadIdx.x - s] : 0;
            __syncthreads();
            sm[threadIdx.x] += t;
            __syncthreads();
        }
        int incl = sm[threadIdx.x];
        int b0 = base;
        if (i < n) {
            int st = b0 + incl - v;   // exclusive prefix
            startv[i] = st;
            cursor[i] = st;
        }
        __syncthreads();
        if (threadIdx.x == 0) base = b0 + sm[1023];
        __syncthreads();
    }
}

__global__ void fill_csr(const int* __restrict__ src, const int* __restrict__ dst,
                         int* __restrict__ cursor, int* __restrict__ csr, int ne) {
    int e = blockIdx.x * blockDim.x + threadIdx.x;
    if (e < ne) {
        int pos = atomicAdd(&cursor[dst[e]], 1);
        csr[pos] = src[e];
    }
}

// ---------------- dense transform: y_self = X@Ws + b, y_neigh = X@Wn ----------------

__global__ void gemm_dual(const float* __restrict__ X, const float* __restrict__ Ws,
                          const float* __restrict__ Wn, const float* __restrict__ Bias,
                          float* __restrict__ Ys, float* __restrict__ Yn, int nrows) {
    int i = blockIdx.x * blockDim.x + threadIdx.x;
    if (i >= nrows * D) return;
    int row = i / D;
    int col = i - row * D;
    const float* xr = X + (size_t)row * D;
    float accS = Bias[col];
    float accN = 0.f;
#pragma unroll 8
    for (int k = 0; k < D; ++k) {
        float xv = xr[k];
        accS = fmaf(xv, Ws[k * D + col], accS);
        accN = fmaf(xv, Wn[k * D + col], accN);
    }
    Ys[i] = accS;
    Yn[i] = accN;
}

// ---------------- aggregation: out[v] = (relu?) y_self[v] + mean_{u in N(v)} y_neigh[u] ----------------

__global__ void agg_combine(const float* __restrict__ Ys, const float* __restrict__ Yn,
                            const int* __restrict__ csr, const int* __restrict__ startv,
                            const int* __restrict__ deg, float* __restrict__ out, int relu) {
    int v = blockIdx.x;
    int t = threadIdx.x;  // 0..95
    int s = startv[v];
    int d = deg[v];
    const int* cp = csr + s;
    float acc = 0.f;
    for (int e = 0; e < d; ++e) {
        int u = cp[e];
        acc += Yn[(size_t)u * D + t];
    }
    float inv = 1.0f / (float)(d > 0 ? d : 1);
    float r = Ys[(size_t)v * D + t] + acc * inv;
    if (relu) r = fmaxf(r, 0.f);
    out[(size_t)v * D + t] = r;
}

// ---------------- launch ----------------

extern "C" void kernel_launch(void* const* d_in, const int* in_sizes, int n_in,
                              void* d_out, int out_size, void* d_ws, size_t ws_size,
                              hipStream_t stream) {
    const float* x   = (const float*)d_in[0];
    const int*   src = (const int*)d_in[1];
    const int*   dst = (const int*)d_in[2];
    const float* Ws1 = (const float*)d_in[3];
    const float* Wn1 = (const float*)d_in[4];
    const float* b1  = (const float*)d_in[5];
    const float* Ws2 = (const float*)d_in[6];
    const float* Wn2 = (const float*)d_in[7];
    const float* b2  = (const float*)d_in[8];
    float* out = (float*)d_out;

    char* w = (char*)d_ws;
    int* deg    = (int*)w; w += (size_t)NN * sizeof(int);
    int* startv = (int*)w; w += (size_t)NN * sizeof(int);
    int* cursor = (int*)w; w += (size_t)NN * sizeof(int);
    int* csr    = (int*)w; w += (size_t)NE * sizeof(int);
    w = (char*)(((uintptr_t)w + 255) & ~(uintptr_t)255);
    float* yself  = (float*)w; w += (size_t)NN * D * sizeof(float);
    float* yneigh = (float*)w; w += (size_t)NN * D * sizeof(float);

    hipMemsetAsync(deg, 0, (size_t)NN * sizeof(int), stream);
    count_deg<<<(NE + 255) / 256, 256, 0, stream>>>(dst, deg, NE);
    scan_deg<<<1, 1024, 0, stream>>>(deg, startv, cursor, NN);
    fill_csr<<<(NE + 255) / 256, 256, 0, stream>>>(src, dst, cursor, csr, NE);

    // layer 1: transform then aggregate (h goes to d_out as scratch)
    gemm_dual<<<(NN * D + 255) / 256, 256, 0, stream>>>(x, Ws1, Wn1, b1, yself, yneigh, NN);
    agg_combine<<<NN, D, 0, stream>>>(yself, yneigh, csr, startv, deg, out, 1);

    // layer 2: transform h (read from d_out) then aggregate into d_out
    gemm_dual<<<(NN * D + 255) / 256, 256, 0, stream>>>(out, Ws2, Wn2, b2, yself, yneigh, NN);
    agg_combine<<<NN, D, 0, stream>>>(yself, yneigh, csr, startv, deg, out, 0);
}

// Round 2
// 294.339 us; speedup vs baseline: 2.2837x; 2.2837x over previous
//
#include <hip/hip_runtime.h>
#include <cstdint>
#include <cstddef>

#define NN 50000
#define NE 800000
#define D 96

// ---------------- CSR build ----------------

__global__ void count_deg(const int* __restrict__ dst, int* __restrict__ deg, int ne) {
    int e = blockIdx.x * blockDim.x + threadIdx.x;
    if (e < ne) atomicAdd(&deg[dst[e]], 1);
}

// Parallel scan: each 1024-block scans its chunk, gets a disjoint base range via
// atomic ticket. Segment ORDER across blocks is irrelevant (only disjointness +
// consistency between startv and cursor within one call matters).
__global__ void scan_deg_fused(const int* __restrict__ deg, int* __restrict__ startv,
                               int* __restrict__ cursor, int* __restrict__ gcount, int n) {
    __shared__ int sm[1024];
    __shared__ int base;
    int i = blockIdx.x * 1024 + threadIdx.x;
    int v = (i < n) ? deg[i] : 0;
    sm[threadIdx.x] = v;
    __syncthreads();
    for (int s = 1; s < 1024; s <<= 1) {
        int t = (threadIdx.x >= (unsigned)s) ? sm[threadIdx.x - s] : 0;
        __syncthreads();
        sm[threadIdx.x] += t;
        __syncthreads();
    }
    if (threadIdx.x == 1023) base = atomicAdd(gcount, sm[1023]);
    __syncthreads();
    if (i < n) {
        int st = base + sm[threadIdx.x] - v;   // exclusive within block + block base
        startv[i] = st;
        cursor[i] = st;
    }
}

__global__ void fill_csr(const int* __restrict__ src, const int* __restrict__ dst,
                         int* __restrict__ cursor, int* __restrict__ csr, int ne) {
    int e = blockIdx.x * blockDim.x + threadIdx.x;
    if (e < ne) {
        int pos = atomicAdd(&cursor[dst[e]], 1);
        csr[pos] = src[e];
    }
}

// ---------------- tiled dense transform ----------------
// grid.y = 0: Ys = X@Ws + bias ; grid.y = 1: Yn = X@Wn
// Block: 64 rows x 96 cols, 256 threads, 4x6 micro-tile per thread.
// LDS: X tile transposed [k][row] (pad 68 for b128-aligned conflict-free reads),
//      W tile row-major [k][col].

#define BM 64

__launch_bounds__(256, 2)
__global__ void gemm_tiled(const float* __restrict__ X, const float* __restrict__ Ws,
                           const float* __restrict__ Wn, const float* __restrict__ Bias,
                           float* __restrict__ Ys, float* __restrict__ Yn) {
    __shared__ float Xs[96][68];
    __shared__ float Wsh[96][96];

    const int mat = blockIdx.y;
    const int row0 = blockIdx.x * BM;
    const float* __restrict__ W = mat ? Wn : Ws;
    float* __restrict__ Y = mat ? Yn : Ys;
    const int tid = threadIdx.x;

    // X tile: 64 rows x 96 = 6144 floats, 6 float4 per thread, store transposed
#pragma unroll
    for (int it = 0; it < 6; ++it) {
        int flat = (it * 256 + tid) * 4;       // multiple of 4; rows are 24 float4s
        int r = flat / 96, k = flat - (flat / 96) * 96;
        int gr = row0 + r;
        if (gr >= NN) gr = NN - 1;
        float4 xv = *(const float4*)(X + (size_t)gr * D + k);
        Xs[k][r] = xv.x; Xs[k + 1][r] = xv.y; Xs[k + 2][r] = xv.z; Xs[k + 3][r] = xv.w;
    }
    // W tile: 96x96 = 9216 floats, 9 float4 per thread, row-major direct copy
#pragma unroll
    for (int it = 0; it < 9; ++it) {
        int flat = (it * 256 + tid) * 4;
        *(float4*)(&Wsh[0][0] + flat) = *(const float4*)(W + flat);
    }
    __syncthreads();

    const int tx = tid & 15;        // 16 col-groups of 6
    const int ty = tid >> 4;        // 16 row-groups of 4
    const int c0 = tx * 6;

    float acc[4][6];
#pragma unroll
    for (int i = 0; i < 4; ++i)
#pragma unroll
        for (int j = 0; j < 6; ++j)
            acc[i][j] = mat ? 0.f : Bias[c0 + j];

#pragma unroll 4
    for (int k = 0; k < 96; ++k) {
        float4 xv = *(const float4*)&Xs[k][ty * 4];
        float2 wa = *(const float2*)&Wsh[k][c0];
        float2 wb = *(const float2*)&Wsh[k][c0 + 2];
        float2 wc = *(const float2*)&Wsh[k][c0 + 4];
        float w[6] = {wa.x, wa.y, wb.x, wb.y, wc.x, wc.y};
        float x[4] = {xv.x, xv.y, xv.z, xv.w};
#pragma unroll
        for (int i = 0; i < 4; ++i)
#pragma unroll
            for (int j = 0; j < 6; ++j)
                acc[i][j] = fmaf(x[i], w[j], acc[i][j]);
    }

#pragma unroll
    for (int i = 0; i < 4; ++i) {
        int gr = row0 + ty * 4 + i;
        if (gr < NN) {
            float* yp = Y + (size_t)gr * D + c0;
            *(float2*)(yp)     = make_float2(acc[i][0], acc[i][1]);
            *(float2*)(yp + 2) = make_float2(acc[i][2], acc[i][3]);
            *(float2*)(yp + 4) = make_float2(acc[i][4], acc[i][5]);
        }
    }
}

// ---------------- aggregation: out[v] = (relu?)(Ys[v] + mean_{u in N(v)} Yn[u]) ----------------
// 4 nodes per 256-thread block, one full wave per node. Lane covers col=lane and
// (lane<32) col=64+lane. 2-way unrolled edge loop with dual accumulators for ILP.

__global__ void agg4(const float* __restrict__ Ys, const float* __restrict__ Yn,
                     const int* __restrict__ csr, const int* __restrict__ startv,
                     const int* __restrict__ deg, float* __restrict__ out, int relu) {
    const int wave = threadIdx.x >> 6;
    const int lane = threadIdx.x & 63;
    const int v = blockIdx.x * 4 + wave;
    const int s = startv[v];
    const int d = deg[v];
    const int* cp = csr + s;

    float a0 = 0.f, a1 = 0.f, b0 = 0.f, b1 = 0.f;
    int e = 0;
    for (; e + 1 < d; e += 2) {
        int u0 = cp[e], u1 = cp[e + 1];
        const float* y0 = Yn + (size_t)u0 * D;
        const float* y1 = Yn + (size_t)u1 * D;
        a0 += y0[lane];
        b0 += y1[lane];
        if (lane < 32) { a1 += y0[64 + lane]; b1 += y1[64 + lane]; }
    }
    if (e < d) {
        const float* y0 = Yn + (size_t)cp[e] * D;
        a0 += y0[lane];
        if (lane < 32) a1 += y0[64 + lane];
    }
    a0 += b0; a1 += b1;

    const float inv = 1.f / (float)(d > 0 ? d : 1);
    const size_t o = (size_t)v * D;
    float r0 = Ys[o + lane] + a0 * inv;
    if (relu) r0 = fmaxf(r0, 0.f);
    out[o + lane] = r0;
    if (lane < 32) {
        float r1 = Ys[o + 64 + lane] + a1 * inv;
        if (relu) r1 = fmaxf(r1, 0.f);
        out[o + 64 + lane] = r1;
    }
}

// ---------------- launch ----------------

extern "C" void kernel_launch(void* const* d_in, const int* in_sizes, int n_in,
                              void* d_out, int out_size, void* d_ws, size_t ws_size,
                              hipStream_t stream) {
    const float* x   = (const float*)d_in[0];
    const int*   src = (const int*)d_in[1];
    const int*   dst = (const int*)d_in[2];
    const float* Ws1 = (const float*)d_in[3];
    const float* Wn1 = (const float*)d_in[4];
    const float* b1  = (const float*)d_in[5];
    const float* Ws2 = (const float*)d_in[6];
    const float* Wn2 = (const float*)d_in[7];
    const float* b2  = (const float*)d_in[8];
    float* out = (float*)d_out;

    char* w = (char*)d_ws;
    int* deg    = (int*)w; w += (size_t)NN * sizeof(int);
    int* gcount = (int*)w; w += sizeof(int);
    int* startv = (int*)w; w += (size_t)NN * sizeof(int);
    int* cursor = (int*)w; w += (size_t)NN * sizeof(int);
    int* csr    = (int*)w; w += (size_t)NE * sizeof(int);
    w = (char*)(((uintptr_t)w + 255) & ~(uintptr_t)255);
    float* yself  = (float*)w; w += (size_t)NN * D * sizeof(float);
    float* yneigh = (float*)w; w += (size_t)NN * D * sizeof(float);

    // zero deg + gcount in one memset (they are adjacent)
    hipMemsetAsync(deg, 0, ((size_t)NN + 1) * sizeof(int), stream);
    count_deg<<<(NE + 255) / 256, 256, 0, stream>>>(dst, deg, NE);
    scan_deg_fused<<<49, 1024, 0, stream>>>(deg, startv, cursor, gcount, NN);
    fill_csr<<<(NE + 255) / 256, 256, 0, stream>>>(src, dst, cursor, csr, NE);

    dim3 ggrid((NN + BM - 1) / BM, 2);

    // layer 1
    gemm_tiled<<<ggrid, 256, 0, stream>>>(x, Ws1, Wn1, b1, yself, yneigh);
    agg4<<<NN / 4, 256, 0, stream>>>(yself, yneigh, csr, startv, deg, out, 1);

    // layer 2 (input = out)
    gemm_tiled<<<ggrid, 256, 0, stream>>>(out, Ws2, Wn2, b2, yself, yneigh);
    agg4<<<NN / 4, 256, 0, stream>>>(yself, yneigh, csr, startv, deg, out, 0);
}

// Round 4
// 271.424 us; speedup vs baseline: 2.4765x; 1.0844x over previous
//
#include <hip/hip_runtime.h>
#include <cstdint>
#include <cstddef>

#define NN 50000
#define NE 800000
#define D 96
#define SCAN_BLOCKS 49   // ceil(50000/1024)

// ---------------- CSR build (deterministic layout) ----------------

__global__ void count_deg(const int* __restrict__ dst, int* __restrict__ deg, int ne) {
    int e = blockIdx.x * blockDim.x + threadIdx.x;
    if (e < ne) atomicAdd(&deg[dst[e]], 1);
}

// Phase 1: per-block exclusive scan (in-place into startv) + block totals.
__global__ void scan_part(const int* __restrict__ deg, int* __restrict__ startv,
                          int* __restrict__ btot, int n) {
    __shared__ int sm[1024];
    int i = blockIdx.x * 1024 + threadIdx.x;
    int v = (i < n) ? deg[i] : 0;
    sm[threadIdx.x] = v;
    __syncthreads();
    for (int s = 1; s < 1024; s <<= 1) {
        int t = (threadIdx.x >= (unsigned)s) ? sm[threadIdx.x - s] : 0;
        __syncthreads();
        sm[threadIdx.x] += t;
        __syncthreads();
    }
    if (i < n) startv[i] = sm[threadIdx.x] - v;   // block-local exclusive
    if (threadIdx.x == 1023) btot[blockIdx.x] = sm[1023];
}

// Phase 2: serial exclusive scan of block totals (49 values, deterministic).
__global__ void scan_base(const int* __restrict__ btot, int* __restrict__ bbase, int nb) {
    if (threadIdx.x == 0) {
        int run = 0;
        for (int b = 0; b < nb; ++b) { bbase[b] = run; run += btot[b]; }
    }
}

// Phase 3: add block base; produce final startv and cursor.
__global__ void scan_apply(const int* __restrict__ bbase, int* __restrict__ startv,
                           int* __restrict__ cursor, int n) {
    int i = blockIdx.x * 1024 + threadIdx.x;
    if (i < n) {
        int st = startv[i] + bbase[blockIdx.x];
        startv[i] = st;
        cursor[i] = st;
    }
}

__global__ void fill_csr(const int* __restrict__ src, const int* __restrict__ dst,
                         int* __restrict__ cursor, int* __restrict__ csr, int ne) {
    int e = blockIdx.x * blockDim.x + threadIdx.x;
    if (e < ne) {
        int pos = atomicAdd(&cursor[dst[e]], 1);
        csr[pos] = src[e];
    }
}

// ---------------- bf16 pack (RTNE) ----------------

__device__ inline uint32_t pack2_bf16(float a, float b) {
    uint32_t ua = __float_as_uint(a), ub = __float_as_uint(b);
    ua = (ua + 0x7fffu + ((ua >> 16) & 1u)) >> 16;
    ub = (ub + 0x7fffu + ((ub >> 16) & 1u)) >> 16;
    return ua | (ub << 16);
}

// ---------------- tiled dense transforms ----------------
// Block: 64 rows x 96 cols, 256 threads, 4x6 micro-tile per thread.
// LDS: X tile transposed [k][row] (pad 68), W tile row-major [k][col].

#define BM 64

template <int MAT>   // 0: Ys = X@W + bias (f32). 1: Yn = X@W (packed bf16 pairs).
__launch_bounds__(256, 2)
__global__ void gemm_tiled(const float* __restrict__ X, const float* __restrict__ W,
                           const float* __restrict__ Bias,
                           float* __restrict__ Ys, uint32_t* __restrict__ Yn2) {
    __shared__ float Xs[96][68];
    __shared__ float Wsh[96][96];

    const int row0 = blockIdx.x * BM;
    const int tid = threadIdx.x;

    // X tile: 64 rows x 96 = 6144 floats, 6 float4 per thread, store transposed
#pragma unroll
    for (int it = 0; it < 6; ++it) {
        int flat = (it * 256 + tid) * 4;       // multiple of 4; rows are 24 float4s
        int r = flat / 96, k = flat - (flat / 96) * 96;
        int gr = row0 + r;
        if (gr >= NN) gr = NN - 1;
        float4 xv = *(const float4*)(X + (size_t)gr * D + k);
        Xs[k][r] = xv.x; Xs[k + 1][r] = xv.y; Xs[k + 2][r] = xv.z; Xs[k + 3][r] = xv.w;
    }
    // W tile: 96x96 = 9216 floats, 9 float4 per thread
#pragma unroll
    for (int it = 0; it < 9; ++it) {
        int flat = (it * 256 + tid) * 4;
        *(float4*)(&Wsh[0][0] + flat) = *(const float4*)(W + flat);
    }
    __syncthreads();

    const int tx = tid & 15;        // 16 col-groups of 6
    const int ty = tid >> 4;        // 16 row-groups of 4
    const int c0 = tx * 6;

    float acc[4][6];
#pragma unroll
    for (int i = 0; i < 4; ++i)
#pragma unroll
        for (int j = 0; j < 6; ++j)
            acc[i][j] = MAT ? 0.f : Bias[c0 + j];

#pragma unroll 4
    for (int k = 0; k < 96; ++k) {
        float4 xv = *(const float4*)&Xs[k][ty * 4];
        float2 wa = *(const float2*)&Wsh[k][c0];
        float2 wb = *(const float2*)&Wsh[k][c0 + 2];
        float2 wc = *(const float2*)&Wsh[k][c0 + 4];
        float w[6] = {wa.x, wa.y, wb.x, wb.y, wc.x, wc.y};
        float x[4] = {xv.x, xv.y, xv.z, xv.w};
#pragma unroll
        for (int i = 0; i < 4; ++i)
#pragma unroll
            for (int j = 0; j < 6; ++j)
                acc[i][j] = fmaf(x[i], w[j], acc[i][j]);
    }

#pragma unroll
    for (int i = 0; i < 4; ++i) {
        int gr = row0 + ty * 4 + i;
        if (gr < NN) {
            if (MAT) {
                uint32_t* yp = Yn2 + (size_t)gr * 48 + (c0 >> 1);
                yp[0] = pack2_bf16(acc[i][0], acc[i][1]);
                yp[1] = pack2_bf16(acc[i][2], acc[i][3]);
                yp[2] = pack2_bf16(acc[i][4], acc[i][5]);
            } else {
                float* yp = Ys + (size_t)gr * D + c0;
                *(float2*)(yp)     = make_float2(acc[i][0], acc[i][1]);
                *(float2*)(yp + 2) = make_float2(acc[i][2], acc[i][3]);
                *(float2*)(yp + 4) = make_float2(acc[i][4], acc[i][5]);
            }
        }
    }
}

// ---------------- aggregation ----------------
// out[v] = (relu?)(Ys[v] + mean_{u in N(v)} Yn[u]); Yn stored as 48 bf16-pairs/row.
// One wave per node; lanes 0..47 own cols {2l, 2l+1}. 4-deep unroll for latency.

__global__ void agg4(const float* __restrict__ Ys, const uint32_t* __restrict__ Yn2,
                     const int* __restrict__ csr, const int* __restrict__ startv,
                     const int* __restrict__ deg, float* __restrict__ out, int relu) {
    const int wave = threadIdx.x >> 6;
    const int lane = threadIdx.x & 63;
    const int v = blockIdx.x * 4 + wave;
    const int s = startv[v];
    const int d = deg[v];
    const int* cp = csr + s;
    const int li = (lane < 48) ? lane : 0;

    float2 a = {0.f, 0.f}, b = {0.f, 0.f}, c = {0.f, 0.f}, g = {0.f, 0.f};
    int e = 0;
    for (; e + 3 < d; e += 4) {
        int u0 = cp[e], u1 = cp[e + 1], u2 = cp[e + 2], u3 = cp[e + 3];
        uint32_t w0 = Yn2[(size_t)u0 * 48 + li];
        uint32_t w1 = Yn2[(size_t)u1 * 48 + li];
        uint32_t w2 = Yn2[(size_t)u2 * 48 + li];
        uint32_t w3 = Yn2[(size_t)u3 * 48 + li];
        a.x += __uint_as_float(w0 << 16); a.y += __uint_as_float(w0 & 0xffff0000u);
        b.x += __uint_as_float(w1 << 16); b.y += __uint_as_float(w1 & 0xffff0000u);
        c.x += __uint_as_float(w2 << 16); c.y += __uint_as_float(w2 & 0xffff0000u);
        g.x += __uint_as_float(w3 << 16); g.y += __uint_as_float(w3 & 0xffff0000u);
    }
    for (; e < d; ++e) {
        uint32_t w = Yn2[(size_t)cp[e] * 48 + li];
        a.x += __uint_as_float(w << 16); a.y += __uint_as_float(w & 0xffff0000u);
    }
    a.x += b.x + c.x + g.x;
    a.y += b.y + c.y + g.y;

    const float inv = 1.f / (float)(d > 0 ? d : 1);
    if (lane < 48) {
        const size_t o = (size_t)v * D + 2 * lane;
        float r0 = Ys[o] + a.x * inv;
        float r1 = Ys[o + 1] + a.y * inv;
        if (relu) { r0 = fmaxf(r0, 0.f); r1 = fmaxf(r1, 0.f); }
        out[o] = r0;
        out[o + 1] = r1;
    }
}

// ---------------- launch ----------------

extern "C" void kernel_launch(void* const* d_in, const int* in_sizes, int n_in,
                              void* d_out, int out_size, void* d_ws, size_t ws_size,
                              hipStream_t stream) {
    const float* x   = (const float*)d_in[0];
    const int*   src = (const int*)d_in[1];
    const int*   dst = (const int*)d_in[2];
    const float* Ws1 = (const float*)d_in[3];
    const float* Wn1 = (const float*)d_in[4];
    const float* b1  = (const float*)d_in[5];
    const float* Ws2 = (const float*)d_in[6];
    const float* Wn2 = (const float*)d_in[7];
    const float* b2  = (const float*)d_in[8];
    float* out = (float*)d_out;

    char* w = (char*)d_ws;
    int* deg    = (int*)w; w += (size_t)NN * sizeof(int);
    int* startv = (int*)w; w += (size_t)NN * sizeof(int);
    int* cursor = (int*)w; w += (size_t)NN * sizeof(int);
    int* btot   = (int*)w; w += (size_t)SCAN_BLOCKS * sizeof(int);
    int* bbase  = (int*)w; w += (size_t)SCAN_BLOCKS * sizeof(int);
    int* csr    = (int*)w; w += (size_t)NE * sizeof(int);
    w = (char*)(((uintptr_t)w + 255) & ~(uintptr_t)255);
    float*    yself  = (float*)w;    w += (size_t)NN * D * sizeof(float);
    uint32_t* yneigh = (uint32_t*)w; w += (size_t)NN * 48 * sizeof(uint32_t);

    hipMemsetAsync(deg, 0, (size_t)NN * sizeof(int), stream);
    count_deg<<<(NE + 255) / 256, 256, 0, stream>>>(dst, deg, NE);
    scan_part<<<SCAN_BLOCKS, 1024, 0, stream>>>(deg, startv, btot, NN);
    scan_base<<<1, 64, 0, stream>>>(btot, bbase, SCAN_BLOCKS);
    scan_apply<<<SCAN_BLOCKS, 1024, 0, stream>>>(bbase, startv, cursor, NN);
    fill_csr<<<(NE + 255) / 256, 256, 0, stream>>>(src, dst, cursor, csr, NE);

    const int ggrid = (NN + BM - 1) / BM;

    // layer 1
    gemm_tiled<0><<<ggrid, 256, 0, stream>>>(x, Ws1, b1, yself, yneigh);
    gemm_tiled<1><<<ggrid, 256, 0, stream>>>(x, Wn1, b1, yself, yneigh);
    agg4<<<NN / 4, 256, 0, stream>>>(yself, yneigh, csr, startv, deg, out, 1);

    // layer 2 (input = out)
    gemm_tiled<0><<<ggrid, 256, 0, stream>>>(out, Ws2, b2, yself, yneigh);
    gemm_tiled<1><<<ggrid, 256, 0, stream>>>(out, Wn2, b2, yself, yneigh);
    agg4<<<NN / 4, 256, 0, stream>>>(yself, yneigh, csr, startv, deg, out, 0);
}

// Round 5
// 259.488 us; speedup vs baseline: 2.5904x; 1.0460x over previous
//
#include <hip/hip_runtime.h>
#include <cstdint>
#include <cstddef>

#define NN 50000
#define NE 800000
#define D 96
#define SCAN_BLOCKS 49   // ceil(50000/1024)

#define NPART 8
#define RANGE 6250       // NN / NPART
#define EPB 8192         // edges per chunk
#define NCHUNK 98        // ceil(NE/EPB)

// ---------------- CSR build (deterministic layout, XCD-partitioned) ----------------
// Block b: partition p = b&7 (maps to one XCD under round-robin dispatch),
// edge chunk c = b>>3. Only edges with dst in range p are counted/written, so
// every deg/cursor/csr cache line is touched by a single XCD -> no line bouncing.

__global__ void count_deg_part(const int* __restrict__ dst, int* __restrict__ deg) {
    const int part = blockIdx.x & (NPART - 1);
    const int chunk = blockIdx.x >> 3;
    const int lo = part * RANGE;
    const int hi = lo + RANGE < NN ? lo + RANGE : NN;
    const int base = chunk * EPB + (int)threadIdx.x * 4;
#pragma unroll
    for (int s = 0; s < EPB / 1024; ++s) {
        int e = base + s * 1024;
        if (e + 3 < NE) {
            int4 d4 = *(const int4*)(dst + e);
            if (d4.x >= lo && d4.x < hi) atomicAdd(&deg[d4.x], 1);
            if (d4.y >= lo && d4.y < hi) atomicAdd(&deg[d4.y], 1);
            if (d4.z >= lo && d4.z < hi) atomicAdd(&deg[d4.z], 1);
            if (d4.w >= lo && d4.w < hi) atomicAdd(&deg[d4.w], 1);
        } else {
            for (int k = 0; k < 4; ++k) {
                if (e + k < NE) {
                    int d = dst[e + k];
                    if (d >= lo && d < hi) atomicAdd(&deg[d], 1);
                }
            }
        }
    }
}

// Phase 1: per-block exclusive scan (in-place into startv) + block totals.
__global__ void scan_part(const int* __restrict__ deg, int* __restrict__ startv,
                          int* __restrict__ btot, int n) {
    __shared__ int sm[1024];
    int i = blockIdx.x * 1024 + threadIdx.x;
    int v = (i < n) ? deg[i] : 0;
    sm[threadIdx.x] = v;
    __syncthreads();
    for (int s = 1; s < 1024; s <<= 1) {
        int t = (threadIdx.x >= (unsigned)s) ? sm[threadIdx.x - s] : 0;
        __syncthreads();
        sm[threadIdx.x] += t;
        __syncthreads();
    }
    if (i < n) startv[i] = sm[threadIdx.x] - v;   // block-local exclusive
    if (threadIdx.x == 1023) btot[blockIdx.x] = sm[1023];
}

// Phase 2: exclusive scan of the 49 block totals via one wave shuffle-scan.
__global__ void scan_base(const int* __restrict__ btot, int* __restrict__ bbase, int nb) {
    int lane = threadIdx.x;   // 64 threads
    int v = (lane < nb) ? btot[lane] : 0;
    int sum = v;
    for (int s = 1; s < 64; s <<= 1) {
        int t = __shfl_up(sum, s, 64);
        if (lane >= s) sum += t;
    }
    if (lane < nb) bbase[lane] = sum - v;
}

// Phase 3: add block base; produce final startv and cursor.
__global__ void scan_apply(const int* __restrict__ bbase, int* __restrict__ startv,
                           int* __restrict__ cursor, int n) {
    int i = blockIdx.x * 1024 + threadIdx.x;
    if (i < n) {
        int st = startv[i] + bbase[blockIdx.x];
        startv[i] = st;
        cursor[i] = st;
    }
}

__global__ void fill_csr_part(const int* __restrict__ src, const int* __restrict__ dst,
                              int* __restrict__ cursor, int* __restrict__ csr) {
    const int part = blockIdx.x & (NPART - 1);
    const int chunk = blockIdx.x >> 3;
    const int lo = part * RANGE;
    const int hi = lo + RANGE < NN ? lo + RANGE : NN;
    const int base = chunk * EPB + (int)threadIdx.x * 4;
#pragma unroll
    for (int s = 0; s < EPB / 1024; ++s) {
        int e = base + s * 1024;
        if (e + 3 < NE) {
            int4 d4 = *(const int4*)(dst + e);
            int4 s4 = *(const int4*)(src + e);
            if (d4.x >= lo && d4.x < hi) csr[atomicAdd(&cursor[d4.x], 1)] = s4.x;
            if (d4.y >= lo && d4.y < hi) csr[atomicAdd(&cursor[d4.y], 1)] = s4.y;
            if (d4.z >= lo && d4.z < hi) csr[atomicAdd(&cursor[d4.z], 1)] = s4.z;
            if (d4.w >= lo && d4.w < hi) csr[atomicAdd(&cursor[d4.w], 1)] = s4.w;
        } else {
            for (int k = 0; k < 4; ++k) {
                if (e + k < NE) {
                    int d = dst[e + k];
                    if (d >= lo && d < hi) csr[atomicAdd(&cursor[d], 1)] = src[e + k];
                }
            }
        }
    }
}

// ---------------- bf16 pack (RTNE) ----------------

__device__ inline uint32_t pack2_bf16(float a, float b) {
    uint32_t ua = __float_as_uint(a), ub = __float_as_uint(b);
    ua = (ua + 0x7fffu + ((ua >> 16) & 1u)) >> 16;
    ub = (ub + 0x7fffu + ((ub >> 16) & 1u)) >> 16;
    return ua | (ub << 16);
}

// ---------------- tiled dense transforms ----------------
// Block: 64 rows x 96 cols, 256 threads, 4x6 micro-tile per thread.
// LDS: X tile transposed [k][row] (pad 68), W tile row-major [k][col].

#define BM 64

template <int MAT>   // 0: Ys = X@W + bias (f32). 1: Yn = X@W (packed bf16 pairs).
__launch_bounds__(256, 2)
__global__ void gemm_tiled(const float* __restrict__ X, const float* __restrict__ W,
                           const float* __restrict__ Bias,
                           float* __restrict__ Ys, uint32_t* __restrict__ Yn2) {
    __shared__ float Xs[96][68];
    __shared__ float Wsh[96][96];

    const int row0 = blockIdx.x * BM;
    const int tid = threadIdx.x;

#pragma unroll
    for (int it = 0; it < 6; ++it) {
        int flat = (it * 256 + tid) * 4;       // multiple of 4; rows are 24 float4s
        int r = flat / 96, k = flat - (flat / 96) * 96;
        int gr = row0 + r;
        if (gr >= NN) gr = NN - 1;
        float4 xv = *(const float4*)(X + (size_t)gr * D + k);
        Xs[k][r] = xv.x; Xs[k + 1][r] = xv.y; Xs[k + 2][r] = xv.z; Xs[k + 3][r] = xv.w;
    }
#pragma unroll
    for (int it = 0; it < 9; ++it) {
        int flat = (it * 256 + tid) * 4;
        *(float4*)(&Wsh[0][0] + flat) = *(const float4*)(W + flat);
    }
    __syncthreads();

    const int tx = tid & 15;        // 16 col-groups of 6
    const int ty = tid >> 4;        // 16 row-groups of 4
    const int c0 = tx * 6;

    float acc[4][6];
#pragma unroll
    for (int i = 0; i < 4; ++i)
#pragma unroll
        for (int j = 0; j < 6; ++j)
            acc[i][j] = MAT ? 0.f : Bias[c0 + j];

#pragma unroll 4
    for (int k = 0; k < 96; ++k) {
        float4 xv = *(const float4*)&Xs[k][ty * 4];
        float2 wa = *(const float2*)&Wsh[k][c0];
        float2 wb = *(const float2*)&Wsh[k][c0 + 2];
        float2 wc = *(const float2*)&Wsh[k][c0 + 4];
        float w[6] = {wa.x, wa.y, wb.x, wb.y, wc.x, wc.y};
        float x[4] = {xv.x, xv.y, xv.z, xv.w};
#pragma unroll
        for (int i = 0; i < 4; ++i)
#pragma unroll
            for (int j = 0; j < 6; ++j)
                acc[i][j] = fmaf(x[i], w[j], acc[i][j]);
    }

#pragma unroll
    for (int i = 0; i < 4; ++i) {
        int gr = row0 + ty * 4 + i;
        if (gr < NN) {
            if (MAT) {
                uint32_t* yp = Yn2 + (size_t)gr * 48 + (c0 >> 1);
                yp[0] = pack2_bf16(acc[i][0], acc[i][1]);
                yp[1] = pack2_bf16(acc[i][2], acc[i][3]);
                yp[2] = pack2_bf16(acc[i][4], acc[i][5]);
            } else {
                float* yp = Ys + (size_t)gr * D + c0;
                *(float2*)(yp)     = make_float2(acc[i][0], acc[i][1]);
                *(float2*)(yp + 2) = make_float2(acc[i][2], acc[i][3]);
                *(float2*)(yp + 4) = make_float2(acc[i][4], acc[i][5]);
            }
        }
    }
}

// ---------------- aggregation ----------------
// out[v] = (relu?)(Ys[v] + mean_{u in N(v)} Yn[u]); Yn stored as 48 bf16-pairs/row.
// One wave per node; lanes 0..47 own cols {2l, 2l+1}. 4-deep unroll for latency.

__global__ void agg4(const float* __restrict__ Ys, const uint32_t* __restrict__ Yn2,
                     const int* __restrict__ csr, const int* __restrict__ startv,
                     const int* __restrict__ deg, float* __restrict__ out, int relu) {
    const int wave = threadIdx.x >> 6;
    const int lane = threadIdx.x & 63;
    const int v = blockIdx.x * 4 + wave;
    const int s = startv[v];
    const int d = deg[v];
    const int* cp = csr + s;
    const int li = (lane < 48) ? lane : 0;

    float2 a = {0.f, 0.f}, b = {0.f, 0.f}, c = {0.f, 0.f}, g = {0.f, 0.f};
    int e = 0;
    for (; e + 3 < d; e += 4) {
        int u0 = cp[e], u1 = cp[e + 1], u2 = cp[e + 2], u3 = cp[e + 3];
        uint32_t w0 = Yn2[(size_t)u0 * 48 + li];
        uint32_t w1 = Yn2[(size_t)u1 * 48 + li];
        uint32_t w2 = Yn2[(size_t)u2 * 48 + li];
        uint32_t w3 = Yn2[(size_t)u3 * 48 + li];
        a.x += __uint_as_float(w0 << 16); a.y += __uint_as_float(w0 & 0xffff0000u);
        b.x += __uint_as_float(w1 << 16); b.y += __uint_as_float(w1 & 0xffff0000u);
        c.x += __uint_as_float(w2 << 16); c.y += __uint_as_float(w2 & 0xffff0000u);
        g.x += __uint_as_float(w3 << 16); g.y += __uint_as_float(w3 & 0xffff0000u);
    }
    for (; e < d; ++e) {
        uint32_t w = Yn2[(size_t)cp[e] * 48 + li];
        a.x += __uint_as_float(w << 16); a.y += __uint_as_float(w & 0xffff0000u);
    }
    a.x += b.x + c.x + g.x;
    a.y += b.y + c.y + g.y;

    const float inv = 1.f / (float)(d > 0 ? d : 1);
    if (lane < 48) {
        const size_t o = (size_t)v * D + 2 * lane;
        float r0 = Ys[o] + a.x * inv;
        float r1 = Ys[o + 1] + a.y * inv;
        if (relu) { r0 = fmaxf(r0, 0.f); r1 = fmaxf(r1, 0.f); }
        out[o] = r0;
        out[o + 1] = r1;
    }
}

// ---------------- launch ----------------

extern "C" void kernel_launch(void* const* d_in, const int* in_sizes, int n_in,
                              void* d_out, int out_size, void* d_ws, size_t ws_size,
                              hipStream_t stream) {
    const float* x   = (const float*)d_in[0];
    const int*   src = (const int*)d_in[1];
    const int*   dst = (const int*)d_in[2];
    const float* Ws1 = (const float*)d_in[3];
    const float* Wn1 = (const float*)d_in[4];
    const float* b1  = (const float*)d_in[5];
    const float* Ws2 = (const float*)d_in[6];
    const float* Wn2 = (const float*)d_in[7];
    const float* b2  = (const float*)d_in[8];
    float* out = (float*)d_out;

    char* w = (char*)d_ws;
    int* deg    = (int*)w; w += (size_t)NN * sizeof(int);
    int* startv = (int*)w; w += (size_t)NN * sizeof(int);
    int* cursor = (int*)w; w += (size_t)NN * sizeof(int);
    int* btot   = (int*)w; w += (size_t)SCAN_BLOCKS * sizeof(int);
    int* bbase  = (int*)w; w += (size_t)SCAN_BLOCKS * sizeof(int);
    int* csr    = (int*)w; w += (size_t)NE * sizeof(int);
    w = (char*)(((uintptr_t)w + 255) & ~(uintptr_t)255);
    float*    yself  = (float*)w;    w += (size_t)NN * D * sizeof(float);
    uint32_t* yneigh = (uint32_t*)w; w += (size_t)NN * 48 * sizeof(uint32_t);

    hipMemsetAsync(deg, 0, (size_t)NN * sizeof(int), stream);
    count_deg_part<<<NPART * NCHUNK, 256, 0, stream>>>(dst, deg);
    scan_part<<<SCAN_BLOCKS, 1024, 0, stream>>>(deg, startv, btot, NN);
    scan_base<<<1, 64, 0, stream>>>(btot, bbase, SCAN_BLOCKS);
    scan_apply<<<SCAN_BLOCKS, 1024, 0, stream>>>(bbase, startv, cursor, NN);
    fill_csr_part<<<NPART * NCHUNK, 256, 0, stream>>>(src, dst, cursor, csr);

    const int ggrid = (NN + BM - 1) / BM;

    // layer 1
    gemm_tiled<0><<<ggrid, 256, 0, stream>>>(x, Ws1, b1, yself, yneigh);
    gemm_tiled<1><<<ggrid, 256, 0, stream>>>(x, Wn1, b1, yself, yneigh);
    agg4<<<NN / 4, 256, 0, stream>>>(yself, yneigh, csr, startv, deg, out, 1);

    // layer 2 (input = out)
    gemm_tiled<0><<<ggrid, 256, 0, stream>>>(out, Ws2, b2, yself, yneigh);
    gemm_tiled<1><<<ggrid, 256, 0, stream>>>(out, Wn2, b2, yself, yneigh);
    agg4<<<NN / 4, 256, 0, stream>>>(yself, yneigh, csr, startv, deg, out, 0);
}

// Round 6
// 207.870 us; speedup vs baseline: 3.2337x; 1.2483x over previous
//
#include <hip/hip_runtime.h>
#include <cstdint>
#include <cstddef>

#define NN 50000
#define NE 800000
#define D 96
#define SCAN_BLOCKS 49   // ceil(50000/1024)

#define NPART 8
#define RANGE 6250       // NN / NPART
#define EPB 8192         // edges per chunk
#define NCHUNK 98        // ceil(NE/EPB)

typedef __attribute__((ext_vector_type(8))) short bf16x8;
typedef __attribute__((ext_vector_type(4))) float f32x4;

// ---------------- CSR build (deterministic layout, partitioned) ----------------

__global__ void count_deg_part(const int* __restrict__ dst, int* __restrict__ deg) {
    const int part = blockIdx.x & (NPART - 1);
    const int chunk = blockIdx.x >> 3;
    const int lo = part * RANGE;
    const int hi = lo + RANGE < NN ? lo + RANGE : NN;
    const int base = chunk * EPB + (int)threadIdx.x * 4;
#pragma unroll
    for (int s = 0; s < EPB / 1024; ++s) {
        int e = base + s * 1024;
        if (e + 3 < NE) {
            int4 d4 = *(const int4*)(dst + e);
            if (d4.x >= lo && d4.x < hi) atomicAdd(&deg[d4.x], 1);
            if (d4.y >= lo && d4.y < hi) atomicAdd(&deg[d4.y], 1);
            if (d4.z >= lo && d4.z < hi) atomicAdd(&deg[d4.z], 1);
            if (d4.w >= lo && d4.w < hi) atomicAdd(&deg[d4.w], 1);
        } else {
            for (int k = 0; k < 4; ++k) {
                if (e + k < NE) {
                    int d = dst[e + k];
                    if (d >= lo && d < hi) atomicAdd(&deg[d], 1);
                }
            }
        }
    }
}

__global__ void scan_part(const int* __restrict__ deg, int* __restrict__ startv,
                          int* __restrict__ btot, int n) {
    __shared__ int sm[1024];
    int i = blockIdx.x * 1024 + threadIdx.x;
    int v = (i < n) ? deg[i] : 0;
    sm[threadIdx.x] = v;
    __syncthreads();
    for (int s = 1; s < 1024; s <<= 1) {
        int t = (threadIdx.x >= (unsigned)s) ? sm[threadIdx.x - s] : 0;
        __syncthreads();
        sm[threadIdx.x] += t;
        __syncthreads();
    }
    if (i < n) startv[i] = sm[threadIdx.x] - v;   // block-local exclusive
    if (threadIdx.x == 1023) btot[blockIdx.x] = sm[1023];
}

__global__ void scan_base(const int* __restrict__ btot, int* __restrict__ bbase, int nb) {
    int lane = threadIdx.x;   // 64 threads
    int v = (lane < nb) ? btot[lane] : 0;
    int sum = v;
    for (int s = 1; s < 64; s <<= 1) {
        int t = __shfl_up(sum, s, 64);
        if (lane >= s) sum += t;
    }
    if (lane < nb) bbase[lane] = sum - v;
}

__global__ void scan_apply(const int* __restrict__ bbase, int* __restrict__ startv,
                           int* __restrict__ cursor, int n) {
    int i = blockIdx.x * 1024 + threadIdx.x;
    if (i < n) {
        int st = startv[i] + bbase[blockIdx.x];
        startv[i] = st;
        cursor[i] = st;
    }
}

__global__ void fill_csr_part(const int* __restrict__ src, const int* __restrict__ dst,
                              int* __restrict__ cursor, int* __restrict__ csr) {
    const int part = blockIdx.x & (NPART - 1);
    const int chunk = blockIdx.x >> 3;
    const int lo = part * RANGE;
    const int hi = lo + RANGE < NN ? lo + RANGE : NN;
    const int base = chunk * EPB + (int)threadIdx.x * 4;
#pragma unroll
    for (int s = 0; s < EPB / 1024; ++s) {
        int e = base + s * 1024;
        if (e + 3 < NE) {
            int4 d4 = *(const int4*)(dst + e);
            int4 s4 = *(const int4*)(src + e);
            if (d4.x >= lo && d4.x < hi) csr[atomicAdd(&cursor[d4.x], 1)] = s4.x;
            if (d4.y >= lo && d4.y < hi) csr[atomicAdd(&cursor[d4.y], 1)] = s4.y;
            if (d4.z >= lo && d4.z < hi) csr[atomicAdd(&cursor[d4.z], 1)] = s4.z;
            if (d4.w >= lo && d4.w < hi) csr[atomicAdd(&cursor[d4.w], 1)] = s4.w;
        } else {
            for (int k = 0; k < 4; ++k) {
                if (e + k < NE) {
                    int d = dst[e + k];
                    if (d >= lo && d < hi) csr[atomicAdd(&cursor[d], 1)] = src[e + k];
                }
            }
        }
    }
}

// ---------------- bf16 helpers (RTNE) ----------------

__device__ inline uint32_t pack2_bf16(float a, float b) {
    uint32_t ua = __float_as_uint(a), ub = __float_as_uint(b);
    ua = (ua + 0x7fffu + ((ua >> 16) & 1u)) >> 16;
    ub = (ub + 0x7fffu + ((ub >> 16) & 1u)) >> 16;
    return ua | (ub << 16);
}

__device__ inline unsigned short pack1_bf16(float a) {
    uint32_t ua = __float_as_uint(a);
    return (unsigned short)((ua + 0x7fffu + ((ua >> 16) & 1u)) >> 16);
}

// x (f32 [NN][96]) -> xb (bf16 [NN][96]); n8 = NN*96/8 elements of 8
__global__ void cvt_bf16(const float* __restrict__ in, uint32_t* __restrict__ outp, int n8) {
    int i = blockIdx.x * blockDim.x + threadIdx.x;
    if (i >= n8) return;
    float4 f0 = *(const float4*)(in + (size_t)i * 8);
    float4 f1 = *(const float4*)(in + (size_t)i * 8 + 4);
    uint4 o;
    o.x = pack2_bf16(f0.x, f0.y);
    o.y = pack2_bf16(f0.z, f0.w);
    o.z = pack2_bf16(f1.x, f1.y);
    o.w = pack2_bf16(f1.z, f1.w);
    *(uint4*)(outp + (size_t)i * 4) = o;
}

// ---------------- weight repack into MFMA B-fragment order ----------------
// Bfg[(s*12+nt)*64 + l] = 8 bf16: W[k=32s+8*(l>>4)+j][col=16*(nt%6)+(l&15)],
// nt<6 -> Ws, nt>=6 -> Wn. 2304 slots; grid 9x256.

__global__ void repack_w(const float* __restrict__ Ws, const float* __restrict__ Wn,
                         uint32_t* __restrict__ Bfg) {
    int t = blockIdx.x * 256 + threadIdx.x;
    if (t >= 2304) return;
    const int isWn = (t >= 1152);
    const float* __restrict__ W = isWn ? Wn : Ws;
    int tt = isWn ? t - 1152 : t;
    int s = tt / 384;
    int r = tt - s * 384;
    int nt6 = r >> 6;
    int l = r & 63;
    int col = nt6 * 16 + (l & 15);
    int k0 = 32 * s + 8 * (l >> 4);
    float v[8];
#pragma unroll
    for (int j = 0; j < 8; ++j) v[j] = W[(k0 + j) * D + col];
    uint4 o;
    o.x = pack2_bf16(v[0], v[1]);
    o.y = pack2_bf16(v[2], v[3]);
    o.z = pack2_bf16(v[4], v[5]);
    o.w = pack2_bf16(v[6], v[7]);
    int nt = nt6 + (isWn ? 6 : 0);
    int slot = (s * 12 + nt) * 64 + l;
    *(uint4*)(Bfg + (size_t)slot * 4) = o;
}

// ---------------- fused dual transform via MFMA ----------------
// Ys = Xb@Ws + bias (f32), Yn = Xb@Wn (bf16). 64 rows/block, 4 waves, each wave
// a 16-row stripe x 192 cols = 12 tiles of 16x16, K=96 in 3 steps of 32.

__launch_bounds__(256, 2)
__global__ void xform_mfma(const unsigned short* __restrict__ Xb,
                           const uint32_t* __restrict__ Bfg,
                           const float* __restrict__ Bias,
                           float* __restrict__ Ys, unsigned short* __restrict__ Yn) {
    __shared__ uint4 Af[768];   // [w][s][l] lane-consecutive 16B -> conflict-free b128
    const int tid = threadIdx.x;
    const int row0 = blockIdx.x * 64;

#pragma unroll
    for (int i = 0; i < 3; ++i) {
        int slot = tid + 256 * i;
        int l = slot & 63;
        int ws = slot >> 6;
        int w = ws / 3, s = ws - w * 3;
        int gr = row0 + w * 16 + (l & 15);
        if (gr >= NN) gr = NN - 1;
        Af[slot] = *(const uint4*)(Xb + (size_t)gr * D + 32 * s + 8 * (l >> 4));
    }
    __syncthreads();

    const int w = tid >> 6, l = tid & 63;
    const int cl = l & 15;

    bf16x8 a0 = *(const bf16x8*)&Af[(w * 3 + 0) * 64 + l];
    bf16x8 a1 = *(const bf16x8*)&Af[(w * 3 + 1) * 64 + l];
    bf16x8 a2 = *(const bf16x8*)&Af[(w * 3 + 2) * 64 + l];

    f32x4 acc[12];
#pragma unroll
    for (int nt = 0; nt < 6; ++nt) {
        float bv = Bias[nt * 16 + cl];
        acc[nt] = (f32x4){bv, bv, bv, bv};
    }
#pragma unroll
    for (int nt = 6; nt < 12; ++nt) acc[nt] = (f32x4){0.f, 0.f, 0.f, 0.f};

#pragma unroll
    for (int nt = 0; nt < 12; ++nt) {
        bf16x8 b0 = *(const bf16x8*)(Bfg + ((size_t)((0 * 12 + nt) * 64 + l)) * 4);
        bf16x8 b1 = *(const bf16x8*)(Bfg + ((size_t)((1 * 12 + nt) * 64 + l)) * 4);
        bf16x8 b2 = *(const bf16x8*)(Bfg + ((size_t)((2 * 12 + nt) * 64 + l)) * 4);
        acc[nt] = __builtin_amdgcn_mfma_f32_16x16x32_bf16(a0, b0, acc[nt], 0, 0, 0);
        acc[nt] = __builtin_amdgcn_mfma_f32_16x16x32_bf16(a1, b1, acc[nt], 0, 0, 0);
        acc[nt] = __builtin_amdgcn_mfma_f32_16x16x32_bf16(a2, b2, acc[nt], 0, 0, 0);
    }

    const int grb = row0 + w * 16 + (l >> 4) * 4;   // C/D: row=(lane>>4)*4+reg, col=lane&15
#pragma unroll
    for (int nt = 0; nt < 6; ++nt) {
#pragma unroll
        for (int rg = 0; rg < 4; ++rg) {
            int gr = grb + rg;
            if (gr < NN) Ys[(size_t)gr * D + nt * 16 + cl] = acc[nt][rg];
        }
    }
#pragma unroll
    for (int nt = 6; nt < 12; ++nt) {
#pragma unroll
        for (int rg = 0; rg < 4; ++rg) {
            int gr = grb + rg;
            if (gr < NN) Yn[(size_t)gr * D + (nt - 6) * 16 + cl] = pack1_bf16(acc[nt][rg]);
        }
    }
}

// ---------------- aggregation ----------------
// out[v] = (relu?)(Ys[v] + mean Yn[u]); Yn viewed as u32 pairs [NN][48].
// Optionally also writes h as packed bf16 (input to next layer's transform).

__global__ void agg4(const float* __restrict__ Ys, const uint32_t* __restrict__ Yn2,
                     const int* __restrict__ csr, const int* __restrict__ startv,
                     const int* __restrict__ deg, float* __restrict__ out,
                     uint32_t* __restrict__ hb2, int relu, int write_hb) {
    const int wave = threadIdx.x >> 6;
    const int lane = threadIdx.x & 63;
    const int v = blockIdx.x * 4 + wave;
    const int s = startv[v];
    const int d = deg[v];
    const int* cp = csr + s;
    const int li = (lane < 48) ? lane : 0;

    float2 a = {0.f, 0.f}, b = {0.f, 0.f}, c = {0.f, 0.f}, g = {0.f, 0.f};
    int e = 0;
    for (; e + 3 < d; e += 4) {
        int u0 = cp[e], u1 = cp[e + 1], u2 = cp[e + 2], u3 = cp[e + 3];
        uint32_t w0 = Yn2[(size_t)u0 * 48 + li];
        uint32_t w1 = Yn2[(size_t)u1 * 48 + li];
        uint32_t w2 = Yn2[(size_t)u2 * 48 + li];
        uint32_t w3 = Yn2[(size_t)u3 * 48 + li];
        a.x += __uint_as_float(w0 << 16); a.y += __uint_as_float(w0 & 0xffff0000u);
        b.x += __uint_as_float(w1 << 16); b.y += __uint_as_float(w1 & 0xffff0000u);
        c.x += __uint_as_float(w2 << 16); c.y += __uint_as_float(w2 & 0xffff0000u);
        g.x += __uint_as_float(w3 << 16); g.y += __uint_as_float(w3 & 0xffff0000u);
    }
    for (; e < d; ++e) {
        uint32_t w = Yn2[(size_t)cp[e] * 48 + li];
        a.x += __uint_as_float(w << 16); a.y += __uint_as_float(w & 0xffff0000u);
    }
    a.x += b.x + c.x + g.x;
    a.y += b.y + c.y + g.y;

    const float inv = 1.f / (float)(d > 0 ? d : 1);
    if (lane < 48) {
        const size_t o = (size_t)v * D + 2 * lane;
        float r0 = Ys[o] + a.x * inv;
        float r1 = Ys[o + 1] + a.y * inv;
        if (relu) { r0 = fmaxf(r0, 0.f); r1 = fmaxf(r1, 0.f); }
        out[o] = r0;
        out[o + 1] = r1;
        if (write_hb) hb2[(size_t)v * 48 + lane] = pack2_bf16(r0, r1);
    }
}

// ---------------- launch ----------------

extern "C" void kernel_launch(void* const* d_in, const int* in_sizes, int n_in,
                              void* d_out, int out_size, void* d_ws, size_t ws_size,
                              hipStream_t stream) {
    const float* x   = (const float*)d_in[0];
    const int*   src = (const int*)d_in[1];
    const int*   dst = (const int*)d_in[2];
    const float* Ws1 = (const float*)d_in[3];
    const float* Wn1 = (const float*)d_in[4];
    const float* b1  = (const float*)d_in[5];
    const float* Ws2 = (const float*)d_in[6];
    const float* Wn2 = (const float*)d_in[7];
    const float* b2  = (const float*)d_in[8];
    float* out = (float*)d_out;

    char* w = (char*)d_ws;
    int* deg    = (int*)w; w += (size_t)NN * sizeof(int);
    int* startv = (int*)w; w += (size_t)NN * sizeof(int);
    int* cursor = (int*)w; w += (size_t)NN * sizeof(int);
    int* btot   = (int*)w; w += (size_t)SCAN_BLOCKS * sizeof(int);
    int* bbase  = (int*)w; w += (size_t)SCAN_BLOCKS * sizeof(int);
    int* csr    = (int*)w; w += (size_t)NE * sizeof(int);
    w = (char*)(((uintptr_t)w + 255) & ~(uintptr_t)255);
    uint32_t* xb2    = (uint32_t*)w; w += (size_t)NN * 48 * sizeof(uint32_t);
    uint32_t* hb2    = (uint32_t*)w; w += (size_t)NN * 48 * sizeof(uint32_t);
    float*    yself  = (float*)w;    w += (size_t)NN * D * sizeof(float);
    unsigned short* yneigh = (unsigned short*)w; w += (size_t)NN * D * sizeof(unsigned short);
    uint32_t* bfg1   = (uint32_t*)w; w += 36 * 64 * 4 * sizeof(uint32_t);
    uint32_t* bfg2   = (uint32_t*)w; w += 36 * 64 * 4 * sizeof(uint32_t);

    // CSR build
    hipMemsetAsync(deg, 0, (size_t)NN * sizeof(int), stream);
    count_deg_part<<<NPART * NCHUNK, 256, 0, stream>>>(dst, deg);
    scan_part<<<SCAN_BLOCKS, 1024, 0, stream>>>(deg, startv, btot, NN);
    scan_base<<<1, 64, 0, stream>>>(btot, bbase, SCAN_BLOCKS);
    scan_apply<<<SCAN_BLOCKS, 1024, 0, stream>>>(bbase, startv, cursor, NN);
    fill_csr_part<<<NPART * NCHUNK, 256, 0, stream>>>(src, dst, cursor, csr);

    // input + weight prep
    const int n8 = NN * D / 8;
    cvt_bf16<<<(n8 + 255) / 256, 256, 0, stream>>>(x, xb2, n8);
    repack_w<<<9, 256, 0, stream>>>(Ws1, Wn1, bfg1);
    repack_w<<<9, 256, 0, stream>>>(Ws2, Wn2, bfg2);

    const int xgrid = (NN + 63) / 64;

    // layer 1
    xform_mfma<<<xgrid, 256, 0, stream>>>((const unsigned short*)xb2, bfg1, b1, yself, yneigh);
    agg4<<<NN / 4, 256, 0, stream>>>(yself, (const uint32_t*)yneigh, csr, startv, deg,
                                     out, hb2, 1, 1);

    // layer 2
    xform_mfma<<<xgrid, 256, 0, stream>>>((const unsigned short*)hb2, bfg2, b2, yself, yneigh);
    agg4<<<NN / 4, 256, 0, stream>>>(yself, (const uint32_t*)yneigh, csr, startv, deg,
                                     out, hb2, 0, 0);
}

// Round 7
// 150.394 us; speedup vs baseline: 4.4695x; 1.3822x over previous
//
#include <hip/hip_runtime.h>
#include <cstdint>
#include <cstddef>

#define NN 50000
#define NE 800000
#define D 96

#define NBUCK 512
#define BSH 7                       // bucket = dst >> 7 (128 nodes per bucket)
#define NBU ((NN + 127) >> 7)       // 391 used buckets
#define TILE 8192                   // edges per bin_edges block
#define NTILE ((NE + TILE - 1) / TILE)   // 98
#define MAXB 5120                   // max edges per bucket (avg 2048, sigma ~45)

typedef __attribute__((ext_vector_type(8))) short bf16x8;
typedef __attribute__((ext_vector_type(4))) float f32x4;

// ================= CSR build: two-level LDS counting sort =================

// Pass 1: global bucket histogram (LDS-aggregated).
__global__ void bucket_hist(const int* __restrict__ dst, int* __restrict__ bucketCnt) {
    __shared__ int h[NBUCK];
    for (int i = threadIdx.x; i < NBUCK; i += 256) h[i] = 0;
    __syncthreads();
    const int stride = gridDim.x * 256 * 4;
    for (int i = (blockIdx.x * 256 + (int)threadIdx.x) * 4; i < NE; i += stride) {
        int4 d4 = *(const int4*)(dst + i);   // NE % 4 == 0
        atomicAdd(&h[d4.x >> BSH], 1);
        atomicAdd(&h[d4.y >> BSH], 1);
        atomicAdd(&h[d4.z >> BSH], 1);
        atomicAdd(&h[d4.w >> BSH], 1);
    }
    __syncthreads();
    for (int i = threadIdx.x; i < NBUCK; i += 256)
        if (h[i]) atomicAdd(&bucketCnt[i], h[i]);
}

// Pass 2: exclusive scan of 512 bucket counts -> base & cursor.
__global__ void bucket_scan(const int* __restrict__ bucketCnt, int* __restrict__ bucketBase,
                            int* __restrict__ bucketCur) {
    __shared__ int sm[NBUCK];
    const int t = threadIdx.x;      // 512 threads
    const int v = bucketCnt[t];
    sm[t] = v;
    __syncthreads();
    for (int s = 1; s < NBUCK; s <<= 1) {
        int u = (t >= s) ? sm[t - s] : 0;
        __syncthreads();
        sm[t] += u;
        __syncthreads();
    }
    const int excl = sm[t] - v;
    bucketBase[t] = excl;
    bucketCur[t] = excl;
}

// Pass 3: tile-sort edges in LDS, write bucket-contiguous (dst,src) pairs.
__launch_bounds__(512)
__global__ void bin_edges(const int* __restrict__ dst, const int* __restrict__ src,
                          int* __restrict__ bucketCur, uint2* __restrict__ pairBuf) {
    __shared__ int hist[NBUCK];
    __shared__ int segStart[NBUCK];
    __shared__ int lcur[NBUCK];
    __shared__ int segBase[NBUCK];
    __shared__ uint2 lpair[TILE];   // 64 KB
    const int t = threadIdx.x;
    const int e0 = blockIdx.x * TILE;
    const int cnt = (NE - e0 < TILE) ? (NE - e0) : TILE;

    for (int i = t; i < NBUCK; i += 512) hist[i] = 0;
    __syncthreads();

    // phase 1: tile histogram
    for (int i = t * 4; i < cnt; i += 512 * 4) {
        if (i + 3 < cnt) {
            int4 d4 = *(const int4*)(dst + e0 + i);
            atomicAdd(&hist[d4.x >> BSH], 1);
            atomicAdd(&hist[d4.y >> BSH], 1);
            atomicAdd(&hist[d4.z >> BSH], 1);
            atomicAdd(&hist[d4.w >> BSH], 1);
        } else {
            for (int k = i; k < cnt; ++k) atomicAdd(&hist[dst[e0 + k] >> BSH], 1);
        }
    }
    __syncthreads();

    // phase 2: exclusive scan of tile histogram
    {
        const int v = hist[t];
        segStart[t] = v;
        __syncthreads();
        for (int s = 1; s < NBUCK; s <<= 1) {
            int u = (t >= s) ? segStart[t - s] : 0;
            __syncthreads();
            segStart[t] += u;
            __syncthreads();
        }
        int excl = segStart[t] - v;
        __syncthreads();
        segStart[t] = excl;
        lcur[t] = excl;
    }
    __syncthreads();

    // phase 3: scatter pairs into LDS sorted by bucket
    for (int i = t * 4; i < cnt; i += 512 * 4) {
        if (i + 3 < cnt) {
            int4 d4 = *(const int4*)(dst + e0 + i);
            int4 s4 = *(const int4*)(src + e0 + i);
            int p0 = atomicAdd(&lcur[d4.x >> BSH], 1); lpair[p0] = make_uint2(d4.x, s4.x);
            int p1 = atomicAdd(&lcur[d4.y >> BSH], 1); lpair[p1] = make_uint2(d4.y, s4.y);
            int p2 = atomicAdd(&lcur[d4.z >> BSH], 1); lpair[p2] = make_uint2(d4.z, s4.z);
            int p3 = atomicAdd(&lcur[d4.w >> BSH], 1); lpair[p3] = make_uint2(d4.w, s4.w);
        } else {
            for (int k = i; k < cnt; ++k) {
                int d = dst[e0 + k], s = src[e0 + k];
                int p = atomicAdd(&lcur[d >> BSH], 1);
                lpair[p] = make_uint2(d, s);
            }
        }
    }
    __syncthreads();

    // phase 4: reserve global ranges (one atomic per non-empty bucket)
    {
        int c = hist[t];
        segBase[t] = c ? atomicAdd(&bucketCur[t], c) : 0;
    }
    __syncthreads();

    // phase 5: segment-contiguous global write (coalesced within segments)
    for (int k = t; k < cnt; k += 512) {
        uint2 p = lpair[k];
        int b = (int)p.x >> BSH;
        pairBuf[(size_t)segBase[b] + (k - segStart[b])] = p;
    }
}

// Pass 4: per-bucket node-level CSR, all global writes coalesced.
__global__ void csr_build(const uint2* __restrict__ pairBuf, const int* __restrict__ bucketBase,
                          const int* __restrict__ bucketCnt, int* __restrict__ deg,
                          int* __restrict__ startv, int* __restrict__ csr) {
    __shared__ int h[128], ls[128], cur[128];
    __shared__ int lsrc[MAXB];
    const int b = blockIdx.x;
    const int t = threadIdx.x;   // 256
    const int lo = bucketBase[b];
    int cnt = bucketCnt[b];
    if (cnt > MAXB) cnt = MAXB;   // never hit for this instance
    const int node0 = b << BSH;

    if (t < 128) h[t] = 0;
    __syncthreads();
    for (int k = t; k < cnt; k += 256)
        atomicAdd(&h[(int)pairBuf[lo + k].x - node0], 1);
    __syncthreads();
    if (t < 128) ls[t] = h[t];
    __syncthreads();
    for (int s = 1; s < 128; s <<= 1) {
        int u = (t >= s && t < 128) ? ls[t - s] : 0;
        __syncthreads();
        if (t < 128) ls[t] += u;
        __syncthreads();
    }
    if (t < 128) {
        int excl = ls[t] - h[t];
        cur[t] = excl;
        int node = node0 + t;
        if (node < NN) {
            deg[node] = h[t];
            startv[node] = lo + excl;
        }
    }
    __syncthreads();
    for (int k = t; k < cnt; k += 256) {
        uint2 p = pairBuf[lo + k];
        int pos = atomicAdd(&cur[(int)p.x - node0], 1);
        lsrc[pos] = (int)p.y;
    }
    __syncthreads();
    for (int k = t; k < cnt; k += 256) csr[lo + k] = lsrc[k];
}

// ================= bf16 helpers (RTNE) =================

__device__ inline uint32_t pack2_bf16(float a, float b) {
    uint32_t ua = __float_as_uint(a), ub = __float_as_uint(b);
    ua = (ua + 0x7fffu + ((ua >> 16) & 1u)) >> 16;
    ub = (ub + 0x7fffu + ((ub >> 16) & 1u)) >> 16;
    return ua | (ub << 16);
}

__device__ inline unsigned short pack1_bf16(float a) {
    uint32_t ua = __float_as_uint(a);
    return (unsigned short)((ua + 0x7fffu + ((ua >> 16) & 1u)) >> 16);
}

__global__ void cvt_bf16(const float* __restrict__ in, uint32_t* __restrict__ outp, int n8) {
    int i = blockIdx.x * blockDim.x + threadIdx.x;
    if (i >= n8) return;
    float4 f0 = *(const float4*)(in + (size_t)i * 8);
    float4 f1 = *(const float4*)(in + (size_t)i * 8 + 4);
    uint4 o;
    o.x = pack2_bf16(f0.x, f0.y);
    o.y = pack2_bf16(f0.z, f0.w);
    o.z = pack2_bf16(f1.x, f1.y);
    o.w = pack2_bf16(f1.z, f1.w);
    *(uint4*)(outp + (size_t)i * 4) = o;
}

// ================= weight repack into MFMA B-fragment order =================

__global__ void repack_w(const float* __restrict__ Ws, const float* __restrict__ Wn,
                         uint32_t* __restrict__ Bfg) {
    int t = blockIdx.x * 256 + threadIdx.x;
    if (t >= 2304) return;
    const int isWn = (t >= 1152);
    const float* __restrict__ W = isWn ? Wn : Ws;
    int tt = isWn ? t - 1152 : t;
    int s = tt / 384;
    int r = tt - s * 384;
    int nt6 = r >> 6;
    int l = r & 63;
    int col = nt6 * 16 + (l & 15);
    int k0 = 32 * s + 8 * (l >> 4);
    float v[8];
#pragma unroll
    for (int j = 0; j < 8; ++j) v[j] = W[(k0 + j) * D + col];
    uint4 o;
    o.x = pack2_bf16(v[0], v[1]);
    o.y = pack2_bf16(v[2], v[3]);
    o.z = pack2_bf16(v[4], v[5]);
    o.w = pack2_bf16(v[6], v[7]);
    int nt = nt6 + (isWn ? 6 : 0);
    int slot = (s * 12 + nt) * 64 + l;
    *(uint4*)(Bfg + (size_t)slot * 4) = o;
}

// ================= fused dual transform via MFMA =================

__launch_bounds__(256, 2)
__global__ void xform_mfma(const unsigned short* __restrict__ Xb,
                           const uint32_t* __restrict__ Bfg,
                           const float* __restrict__ Bias,
                           float* __restrict__ Ys, unsigned short* __restrict__ Yn) {
    __shared__ uint4 Af[768];
    const int tid = threadIdx.x;
    const int row0 = blockIdx.x * 64;

#pragma unroll
    for (int i = 0; i < 3; ++i) {
        int slot = tid + 256 * i;
        int l = slot & 63;
        int ws = slot >> 6;
        int w = ws / 3, s = ws - w * 3;
        int gr = row0 + w * 16 + (l & 15);
        if (gr >= NN) gr = NN - 1;
        Af[slot] = *(const uint4*)(Xb + (size_t)gr * D + 32 * s + 8 * (l >> 4));
    }
    __syncthreads();

    const int w = tid >> 6, l = tid & 63;
    const int cl = l & 15;

    bf16x8 a0 = *(const bf16x8*)&Af[(w * 3 + 0) * 64 + l];
    bf16x8 a1 = *(const bf16x8*)&Af[(w * 3 + 1) * 64 + l];
    bf16x8 a2 = *(const bf16x8*)&Af[(w * 3 + 2) * 64 + l];

    f32x4 acc[12];
#pragma unroll
    for (int nt = 0; nt < 6; ++nt) {
        float bv = Bias[nt * 16 + cl];
        acc[nt] = (f32x4){bv, bv, bv, bv};
    }
#pragma unroll
    for (int nt = 6; nt < 12; ++nt) acc[nt] = (f32x4){0.f, 0.f, 0.f, 0.f};

#pragma unroll
    for (int nt = 0; nt < 12; ++nt) {
        bf16x8 b0 = *(const bf16x8*)(Bfg + ((size_t)((0 * 12 + nt) * 64 + l)) * 4);
        bf16x8 b1 = *(const bf16x8*)(Bfg + ((size_t)((1 * 12 + nt) * 64 + l)) * 4);
        bf16x8 b2 = *(const bf16x8*)(Bfg + ((size_t)((2 * 12 + nt) * 64 + l)) * 4);
        acc[nt] = __builtin_amdgcn_mfma_f32_16x16x32_bf16(a0, b0, acc[nt], 0, 0, 0);
        acc[nt] = __builtin_amdgcn_mfma_f32_16x16x32_bf16(a1, b1, acc[nt], 0, 0, 0);
        acc[nt] = __builtin_amdgcn_mfma_f32_16x16x32_bf16(a2, b2, acc[nt], 0, 0, 0);
    }

    const int grb = row0 + w * 16 + (l >> 4) * 4;
#pragma unroll
    for (int nt = 0; nt < 6; ++nt) {
#pragma unroll
        for (int rg = 0; rg < 4; ++rg) {
            int gr = grb + rg;
            if (gr < NN) Ys[(size_t)gr * D + nt * 16 + cl] = acc[nt][rg];
        }
    }
#pragma unroll
    for (int nt = 6; nt < 12; ++nt) {
#pragma unroll
        for (int rg = 0; rg < 4; ++rg) {
            int gr = grb + rg;
            if (gr < NN) Yn[(size_t)gr * D + (nt - 6) * 16 + cl] = pack1_bf16(acc[nt][rg]);
        }
    }
}

// ================= aggregation =================

__global__ void agg4(const float* __restrict__ Ys, const uint32_t* __restrict__ Yn2,
                     const int* __restrict__ csr, const int* __restrict__ startv,
                     const int* __restrict__ deg, float* __restrict__ out,
                     uint32_t* __restrict__ hb2, int relu, int write_hb) {
    const int wave = threadIdx.x >> 6;
    const int lane = threadIdx.x & 63;
    const int v = blockIdx.x * 4 + wave;
    const int s = startv[v];
    const int d = deg[v];
    const int* cp = csr + s;
    const int li = (lane < 48) ? lane : 0;

    float2 a = {0.f, 0.f}, b = {0.f, 0.f}, c = {0.f, 0.f}, g = {0.f, 0.f};
    int e = 0;
    for (; e + 3 < d; e += 4) {
        int u0 = cp[e], u1 = cp[e + 1], u2 = cp[e + 2], u3 = cp[e + 3];
        uint32_t w0 = Yn2[(size_t)u0 * 48 + li];
        uint32_t w1 = Yn2[(size_t)u1 * 48 + li];
        uint32_t w2 = Yn2[(size_t)u2 * 48 + li];
        uint32_t w3 = Yn2[(size_t)u3 * 48 + li];
        a.x += __uint_as_float(w0 << 16); a.y += __uint_as_float(w0 & 0xffff0000u);
        b.x += __uint_as_float(w1 << 16); b.y += __uint_as_float(w1 & 0xffff0000u);
        c.x += __uint_as_float(w2 << 16); c.y += __uint_as_float(w2 & 0xffff0000u);
        g.x += __uint_as_float(w3 << 16); g.y += __uint_as_float(w3 & 0xffff0000u);
    }
    for (; e < d; ++e) {
        uint32_t w = Yn2[(size_t)cp[e] * 48 + li];
        a.x += __uint_as_float(w << 16); a.y += __uint_as_float(w & 0xffff0000u);
    }
    a.x += b.x + c.x + g.x;
    a.y += b.y + c.y + g.y;

    const float inv = 1.f / (float)(d > 0 ? d : 1);
    if (lane < 48) {
        const size_t o = (size_t)v * D + 2 * lane;
        float r0 = Ys[o] + a.x * inv;
        float r1 = Ys[o + 1] + a.y * inv;
        if (relu) { r0 = fmaxf(r0, 0.f); r1 = fmaxf(r1, 0.f); }
        out[o] = r0;
        out[o + 1] = r1;
        if (write_hb) hb2[(size_t)v * 48 + lane] = pack2_bf16(r0, r1);
    }
}

// ================= launch =================

extern "C" void kernel_launch(void* const* d_in, const int* in_sizes, int n_in,
                              void* d_out, int out_size, void* d_ws, size_t ws_size,
                              hipStream_t stream) {
    const float* x   = (const float*)d_in[0];
    const int*   src = (const int*)d_in[1];
    const int*   dst = (const int*)d_in[2];
    const float* Ws1 = (const float*)d_in[3];
    const float* Wn1 = (const float*)d_in[4];
    const float* b1  = (const float*)d_in[5];
    const float* Ws2 = (const float*)d_in[6];
    const float* Wn2 = (const float*)d_in[7];
    const float* b2  = (const float*)d_in[8];
    float* out = (float*)d_out;

    char* w = (char*)d_ws;
    int* deg        = (int*)w; w += (size_t)NN * sizeof(int);
    int* startv     = (int*)w; w += (size_t)NN * sizeof(int);
    int* bucketCnt  = (int*)w; w += NBUCK * sizeof(int);
    int* bucketBase = (int*)w; w += NBUCK * sizeof(int);
    int* bucketCur  = (int*)w; w += NBUCK * sizeof(int);
    int* csr        = (int*)w; w += (size_t)NE * sizeof(int);
    w = (char*)(((uintptr_t)w + 255) & ~(uintptr_t)255);
    uint32_t* xb2   = (uint32_t*)w; w += (size_t)NN * 48 * sizeof(uint32_t);
    uint32_t* hb2   = (uint32_t*)w; w += (size_t)NN * 48 * sizeof(uint32_t);
    float*    yself = (float*)w;    w += (size_t)NN * D * sizeof(float);
    unsigned short* yneigh = (unsigned short*)w; w += (size_t)NN * D * sizeof(unsigned short);
    uint32_t* bfg1  = (uint32_t*)w; w += 36 * 64 * 4 * sizeof(uint32_t);
    uint32_t* bfg2  = (uint32_t*)w; w += 36 * 64 * 4 * sizeof(uint32_t);

    // pairBuf aliases yself: pairBuf dead before xform_mfma writes yself.
    uint2* pairBuf = (uint2*)yself;   // NE*8 = 6.4 MB <= 19.2 MB

    // CSR build (two-level LDS counting sort)
    hipMemsetAsync(bucketCnt, 0, NBUCK * sizeof(int), stream);
    bucket_hist<<<256, 256, 0, stream>>>(dst, bucketCnt);
    bucket_scan<<<1, NBUCK, 0, stream>>>(bucketCnt, bucketBase, bucketCur);
    bin_edges<<<NTILE, 512, 0, stream>>>(dst, src, bucketCur, pairBuf);
    csr_build<<<NBU, 256, 0, stream>>>(pairBuf, bucketBase, bucketCnt, deg, startv, csr);

    // input + weight prep
    const int n8 = NN * D / 8;
    cvt_bf16<<<(n8 + 255) / 256, 256, 0, stream>>>(x, xb2, n8);
    repack_w<<<9, 256, 0, stream>>>(Ws1, Wn1, bfg1);
    repack_w<<<9, 256, 0, stream>>>(Ws2, Wn2, bfg2);

    const int xgrid = (NN + 63) / 64;

    // layer 1
    xform_mfma<<<xgrid, 256, 0, stream>>>((const unsigned short*)xb2, bfg1, b1, yself, yneigh);
    agg4<<<NN / 4, 256, 0, stream>>>(yself, (const uint32_t*)yneigh, csr, startv, deg,
                                     out, hb2, 1, 1);

    // layer 2
    xform_mfma<<<xgrid, 256, 0, stream>>>((const unsigned short*)hb2, bfg2, b2, yself, yneigh);
    agg4<<<NN / 4, 256, 0, stream>>>(yself, (const uint32_t*)yneigh, csr, startv, deg,
                                     out, hb2, 0, 0);
}

// Round 8
// 137.521 us; speedup vs baseline: 4.8879x; 1.0936x over previous
//
#include <hip/hip_runtime.h>
#include <cstdint>
#include <cstddef>

#define NN 50000
#define NE 800000
#define D 96

#define NBUCK 512
#define BSH 7                       // bucket = dst >> 7 (128 nodes per bucket)
#define NBU ((NN + 127) >> 7)       // 391 used buckets
#define TILE 8192                   // edges per bin_edges block
#define NTILE ((NE + TILE - 1) / TILE)   // 98
#define MAXB 5120                   // max edges per bucket (avg 2048)

typedef __attribute__((ext_vector_type(8))) short bf16x8;
typedef __attribute__((ext_vector_type(4))) float f32x4;

// ================= CSR build: two-level LDS counting sort =================

__global__ void bucket_hist(const int* __restrict__ dst, int* __restrict__ bucketCnt) {
    __shared__ int h[NBUCK];
    for (int i = threadIdx.x; i < NBUCK; i += 256) h[i] = 0;
    __syncthreads();
    const int stride = gridDim.x * 256 * 4;
    for (int i = (blockIdx.x * 256 + (int)threadIdx.x) * 4; i < NE; i += stride) {
        int4 d4 = *(const int4*)(dst + i);   // NE % 4 == 0
        atomicAdd(&h[d4.x >> BSH], 1);
        atomicAdd(&h[d4.y >> BSH], 1);
        atomicAdd(&h[d4.z >> BSH], 1);
        atomicAdd(&h[d4.w >> BSH], 1);
    }
    __syncthreads();
    for (int i = threadIdx.x; i < NBUCK; i += 256)
        if (h[i]) atomicAdd(&bucketCnt[i], h[i]);
}

__global__ void bucket_scan(const int* __restrict__ bucketCnt, int* __restrict__ bucketBase,
                            int* __restrict__ bucketCur) {
    __shared__ int sm[NBUCK];
    const int t = threadIdx.x;      // 512 threads
    const int v = bucketCnt[t];
    sm[t] = v;
    __syncthreads();
    for (int s = 1; s < NBUCK; s <<= 1) {
        int u = (t >= s) ? sm[t - s] : 0;
        __syncthreads();
        sm[t] += u;
        __syncthreads();
    }
    const int excl = sm[t] - v;
    bucketBase[t] = excl;
    bucketCur[t] = excl;
}

__launch_bounds__(512)
__global__ void bin_edges(const int* __restrict__ dst, const int* __restrict__ src,
                          int* __restrict__ bucketCur, uint2* __restrict__ pairBuf) {
    __shared__ int hist[NBUCK];
    __shared__ int segStart[NBUCK];
    __shared__ int lcur[NBUCK];
    __shared__ int segBase[NBUCK];
    __shared__ uint2 lpair[TILE];   // 64 KB
    const int t = threadIdx.x;
    const int e0 = blockIdx.x * TILE;
    const int cnt = (NE - e0 < TILE) ? (NE - e0) : TILE;

    for (int i = t; i < NBUCK; i += 512) hist[i] = 0;
    __syncthreads();

    for (int i = t * 4; i < cnt; i += 512 * 4) {
        if (i + 3 < cnt) {
            int4 d4 = *(const int4*)(dst + e0 + i);
            atomicAdd(&hist[d4.x >> BSH], 1);
            atomicAdd(&hist[d4.y >> BSH], 1);
            atomicAdd(&hist[d4.z >> BSH], 1);
            atomicAdd(&hist[d4.w >> BSH], 1);
        } else {
            for (int k = i; k < cnt; ++k) atomicAdd(&hist[dst[e0 + k] >> BSH], 1);
        }
    }
    __syncthreads();

    {
        const int v = hist[t];
        segStart[t] = v;
        __syncthreads();
        for (int s = 1; s < NBUCK; s <<= 1) {
            int u = (t >= s) ? segStart[t - s] : 0;
            __syncthreads();
            segStart[t] += u;
            __syncthreads();
        }
        int excl = segStart[t] - v;
        __syncthreads();
        segStart[t] = excl;
        lcur[t] = excl;
    }
    __syncthreads();

    for (int i = t * 4; i < cnt; i += 512 * 4) {
        if (i + 3 < cnt) {
            int4 d4 = *(const int4*)(dst + e0 + i);
            int4 s4 = *(const int4*)(src + e0 + i);
            int p0 = atomicAdd(&lcur[d4.x >> BSH], 1); lpair[p0] = make_uint2(d4.x, s4.x);
            int p1 = atomicAdd(&lcur[d4.y >> BSH], 1); lpair[p1] = make_uint2(d4.y, s4.y);
            int p2 = atomicAdd(&lcur[d4.z >> BSH], 1); lpair[p2] = make_uint2(d4.z, s4.z);
            int p3 = atomicAdd(&lcur[d4.w >> BSH], 1); lpair[p3] = make_uint2(d4.w, s4.w);
        } else {
            for (int k = i; k < cnt; ++k) {
                int d = dst[e0 + k], s = src[e0 + k];
                int p = atomicAdd(&lcur[d >> BSH], 1);
                lpair[p] = make_uint2(d, s);
            }
        }
    }
    __syncthreads();

    {
        int c = hist[t];
        segBase[t] = c ? atomicAdd(&bucketCur[t], c) : 0;
    }
    __syncthreads();

    for (int k = t; k < cnt; k += 512) {
        uint2 p = lpair[k];
        int b = (int)p.x >> BSH;
        pairBuf[(size_t)segBase[b] + (k - segStart[b])] = p;
    }
}

__global__ void csr_build(const uint2* __restrict__ pairBuf, const int* __restrict__ bucketBase,
                          const int* __restrict__ bucketCnt, int* __restrict__ deg,
                          int* __restrict__ startv, int* __restrict__ csr) {
    __shared__ int h[128], ls[128], cur[128];
    __shared__ int lsrc[MAXB];
    const int b = blockIdx.x;
    const int t = threadIdx.x;   // 256
    const int lo = bucketBase[b];
    int cnt = bucketCnt[b];
    if (cnt > MAXB) cnt = MAXB;
    const int node0 = b << BSH;

    if (t < 128) h[t] = 0;
    __syncthreads();
    for (int k = t; k < cnt; k += 256)
        atomicAdd(&h[(int)pairBuf[lo + k].x - node0], 1);
    __syncthreads();
    if (t < 128) ls[t] = h[t];
    __syncthreads();
    for (int s = 1; s < 128; s <<= 1) {
        int u = (t >= s && t < 128) ? ls[t - s] : 0;
        __syncthreads();
        if (t < 128) ls[t] += u;
        __syncthreads();
    }
    if (t < 128) {
        int excl = ls[t] - h[t];
        cur[t] = excl;
        int node = node0 + t;
        if (node < NN) {
            deg[node] = h[t];
            startv[node] = lo + excl;
        }
    }
    __syncthreads();
    for (int k = t; k < cnt; k += 256) {
        uint2 p = pairBuf[lo + k];
        int pos = atomicAdd(&cur[(int)p.x - node0], 1);
        lsrc[pos] = (int)p.y;
    }
    __syncthreads();
    for (int k = t; k < cnt; k += 256) csr[lo + k] = lsrc[k];
}

// ================= bf16 helpers (RTNE) =================

__device__ inline uint32_t pack2_bf16(float a, float b) {
    uint32_t ua = __float_as_uint(a), ub = __float_as_uint(b);
    ua = (ua + 0x7fffu + ((ua >> 16) & 1u)) >> 16;
    ub = (ub + 0x7fffu + ((ub >> 16) & 1u)) >> 16;
    return ua | (ub << 16);
}

__device__ inline unsigned short pack1_bf16(float a) {
    uint32_t ua = __float_as_uint(a);
    return (unsigned short)((ua + 0x7fffu + ((ua >> 16) & 1u)) >> 16);
}

__device__ inline float bf_lo(uint32_t w) { return __uint_as_float(w << 16); }
__device__ inline float bf_hi(uint32_t w) { return __uint_as_float(w & 0xffff0000u); }

// ================= weight repack (both layers) into MFMA B-fragment order =================
// Bfg[(s*12+nt)*64 + l] (uint4) = 8 bf16 of W[k=32s+8*(l>>4)+j][col=16*(nt%6)+(l&15)];
// nt<6 -> Ws, nt>=6 -> Wn.

__global__ void repack_both(const float* __restrict__ Ws1, const float* __restrict__ Wn1,
                            const float* __restrict__ Ws2, const float* __restrict__ Wn2,
                            uint32_t* __restrict__ bfg1, uint32_t* __restrict__ bfg2) {
    int t = blockIdx.x * 256 + threadIdx.x;
    if (t >= 4608) return;
    const int layer = (t >= 2304);
    int tt = t - layer * 2304;
    const int isWn = (tt >= 1152);
    const float* __restrict__ W = layer ? (isWn ? Wn2 : Ws2) : (isWn ? Wn1 : Ws1);
    uint32_t* __restrict__ Bfg = layer ? bfg2 : bfg1;
    tt = isWn ? tt - 1152 : tt;
    int s = tt / 384;
    int r = tt - s * 384;
    int nt6 = r >> 6;
    int l = r & 63;
    int col = nt6 * 16 + (l & 15);
    int k0 = 32 * s + 8 * (l >> 4);
    float v[8];
#pragma unroll
    for (int j = 0; j < 8; ++j) v[j] = W[(k0 + j) * D + col];
    uint4 o;
    o.x = pack2_bf16(v[0], v[1]);
    o.y = pack2_bf16(v[2], v[3]);
    o.z = pack2_bf16(v[4], v[5]);
    o.w = pack2_bf16(v[6], v[7]);
    int nt = nt6 + (isWn ? 6 : 0);
    int slot = (s * 12 + nt) * 64 + l;
    *(uint4*)(Bfg + (size_t)slot * 4) = o;
}

// ================= layer-1 transform: x f32 in, Ys1/Yn1 bf16 out =================

__launch_bounds__(256, 2)
__global__ void xform1_mfma(const float* __restrict__ X,
                            const uint32_t* __restrict__ Bfg,
                            const float* __restrict__ Bias,
                            unsigned short* __restrict__ Ys,   // bf16 [NN][96]
                            unsigned short* __restrict__ Yn) { // bf16 [NN][96]
    __shared__ __align__(16) uint32_t Af[3072];   // 768 fragment slots x 4 u32
    const int tid = threadIdx.x;
    const int row0 = blockIdx.x * 64;

    // stage 64x96 f32 tile, converting to bf16 directly into fragment layout
#pragma unroll
    for (int it = 0; it < 6; ++it) {
        int flat = (it * 256 + tid) * 4;
        int r = flat / 96, k = flat - (flat / 96) * 96;
        int gr = row0 + r;
        if (gr >= NN) gr = NN - 1;
        float4 xv = *(const float4*)(X + (size_t)gr * D + k);
        int wq = r >> 4, s = k >> 5;
        int lq = ((k >> 3) & 3) * 16 + (r & 15);
        int base = ((wq * 3 + s) * 64 + lq) * 4 + ((k & 7) >> 1);
        Af[base] = pack2_bf16(xv.x, xv.y);
        Af[base + 1] = pack2_bf16(xv.z, xv.w);
    }
    __syncthreads();

    const int w = tid >> 6, l = tid & 63;
    const int cl = l & 15;

    bf16x8 a0 = *(const bf16x8*)&Af[((w * 3 + 0) * 64 + l) * 4];
    bf16x8 a1 = *(const bf16x8*)&Af[((w * 3 + 1) * 64 + l) * 4];
    bf16x8 a2 = *(const bf16x8*)&Af[((w * 3 + 2) * 64 + l) * 4];

    f32x4 acc[12];
#pragma unroll
    for (int nt = 0; nt < 6; ++nt) {
        float bv = Bias[nt * 16 + cl];
        acc[nt] = (f32x4){bv, bv, bv, bv};
    }
#pragma unroll
    for (int nt = 6; nt < 12; ++nt) acc[nt] = (f32x4){0.f, 0.f, 0.f, 0.f};

#pragma unroll
    for (int nt = 0; nt < 12; ++nt) {
        bf16x8 b0 = *(const bf16x8*)(Bfg + ((size_t)((0 * 12 + nt) * 64 + l)) * 4);
        bf16x8 b1 = *(const bf16x8*)(Bfg + ((size_t)((1 * 12 + nt) * 64 + l)) * 4);
        bf16x8 b2 = *(const bf16x8*)(Bfg + ((size_t)((2 * 12 + nt) * 64 + l)) * 4);
        acc[nt] = __builtin_amdgcn_mfma_f32_16x16x32_bf16(a0, b0, acc[nt], 0, 0, 0);
        acc[nt] = __builtin_amdgcn_mfma_f32_16x16x32_bf16(a1, b1, acc[nt], 0, 0, 0);
        acc[nt] = __builtin_amdgcn_mfma_f32_16x16x32_bf16(a2, b2, acc[nt], 0, 0, 0);
    }

    const int grb = row0 + w * 16 + (l >> 4) * 4;
#pragma unroll
    for (int nt = 0; nt < 6; ++nt)
#pragma unroll
        for (int rg = 0; rg < 4; ++rg) {
            int gr = grb + rg;
            if (gr < NN) Ys[(size_t)gr * D + nt * 16 + cl] = pack1_bf16(acc[nt][rg]);
        }
#pragma unroll
    for (int nt = 6; nt < 12; ++nt)
#pragma unroll
        for (int rg = 0; rg < 4; ++rg) {
            int gr = grb + rg;
            if (gr < NN) Yn[(size_t)gr * D + (nt - 6) * 16 + cl] = pack1_bf16(acc[nt][rg]);
        }
}

// ================= fused layer-1 aggregation + layer-2 transform =================
// Block = 64 nodes, 8 waves. Phase A: wave w aggregates nodes w*8..w*8+7 ->
// h = relu(Ys1 + mean gather(Yn1)) -> LDS (bf16 pairs, stride 52 u32).
// Phase B: wave w = stripe (w>>1), half (w&1): MFMA h @ W2 -> Ys2 f32 / Yn2 bf16.

__launch_bounds__(512, 2)
__global__ void fused_aggx(const unsigned short* __restrict__ Ys1,
                           const uint32_t* __restrict__ Yn1,
                           const int* __restrict__ csr, const int* __restrict__ startv,
                           const int* __restrict__ deg,
                           const uint32_t* __restrict__ Bfg2, const float* __restrict__ Bias2,
                           float* __restrict__ Ys2, unsigned short* __restrict__ Yn2) {
    __shared__ __align__(16) uint32_t H[64][52];   // 48 used cols; pad -> ~2-way banks
    const int tid = threadIdx.x;
    const int w = tid >> 6, l = tid & 63;
    const int row0 = blockIdx.x * 64;
    const int li = (l < 48) ? l : 0;

    // -------- Phase A --------
    for (int j = 0; j < 8; ++j) {
        const int vl = w * 8 + j;
        const int v = row0 + vl;
        uint32_t hpair = 0;
        if (v < NN) {
            const int s = startv[v];
            const int dg = deg[v];
            const int* cp = csr + s;
            float sx[8], sy[8];
#pragma unroll
            for (int i = 0; i < 8; ++i) { sx[i] = 0.f; sy[i] = 0.f; }
            int e = 0;
            for (; e + 7 < dg; e += 8) {
#pragma unroll
                for (int i = 0; i < 8; ++i) {
                    uint32_t wv = Yn1[(size_t)cp[e + i] * 48 + li];
                    sx[i] += bf_lo(wv); sy[i] += bf_hi(wv);
                }
            }
            for (; e < dg; ++e) {
                uint32_t wv = Yn1[(size_t)cp[e] * 48 + li];
                sx[0] += bf_lo(wv); sy[0] += bf_hi(wv);
            }
            float ax = ((sx[0] + sx[1]) + (sx[2] + sx[3])) + ((sx[4] + sx[5]) + (sx[6] + sx[7]));
            float ay = ((sy[0] + sy[1]) + (sy[2] + sy[3])) + ((sy[4] + sy[5]) + (sy[6] + sy[7]));
            const float inv = 1.f / (float)(dg > 0 ? dg : 1);
            uint32_t ysp = *(const uint32_t*)(Ys1 + (size_t)v * 96 + 2 * li);
            float r0 = fmaxf(bf_lo(ysp) + ax * inv, 0.f);
            float r1 = fmaxf(bf_hi(ysp) + ay * inv, 0.f);
            hpair = pack2_bf16(r0, r1);
        }
        if (l < 48) H[vl][l] = hpair;
    }
    __syncthreads();

    // -------- Phase B --------
    const int stripe = w >> 1;
    const int hf = w & 1;
    const int cl = l & 15;
    const int kq = l >> 4;

    bf16x8 a0 = *(const bf16x8*)&H[stripe * 16 + cl][0 + 4 * kq];
    bf16x8 a1 = *(const bf16x8*)&H[stripe * 16 + cl][16 + 4 * kq];
    bf16x8 a2 = *(const bf16x8*)&H[stripe * 16 + cl][32 + 4 * kq];

    f32x4 acc[6];
#pragma unroll
    for (int nt = 0; nt < 6; ++nt) {
        float bv = hf ? 0.f : Bias2[nt * 16 + cl];
        acc[nt] = (f32x4){bv, bv, bv, bv};
    }
#pragma unroll
    for (int nt = 0; nt < 6; ++nt) {
        int ntg = hf * 6 + nt;
        bf16x8 b0 = *(const bf16x8*)(Bfg2 + ((size_t)((0 * 12 + ntg) * 64 + l)) * 4);
        bf16x8 b1 = *(const bf16x8*)(Bfg2 + ((size_t)((1 * 12 + ntg) * 64 + l)) * 4);
        bf16x8 b2 = *(const bf16x8*)(Bfg2 + ((size_t)((2 * 12 + ntg) * 64 + l)) * 4);
        acc[nt] = __builtin_amdgcn_mfma_f32_16x16x32_bf16(a0, b0, acc[nt], 0, 0, 0);
        acc[nt] = __builtin_amdgcn_mfma_f32_16x16x32_bf16(a1, b1, acc[nt], 0, 0, 0);
        acc[nt] = __builtin_amdgcn_mfma_f32_16x16x32_bf16(a2, b2, acc[nt], 0, 0, 0);
    }

    const int grb = row0 + stripe * 16 + kq * 4;
    if (hf == 0) {
#pragma unroll
        for (int nt = 0; nt < 6; ++nt)
#pragma unroll
            for (int rg = 0; rg < 4; ++rg) {
                int gr = grb + rg;
                if (gr < NN) Ys2[(size_t)gr * D + nt * 16 + cl] = acc[nt][rg];
            }
    } else {
#pragma unroll
        for (int nt = 0; nt < 6; ++nt)
#pragma unroll
            for (int rg = 0; rg < 4; ++rg) {
                int gr = grb + rg;
                if (gr < NN) Yn2[(size_t)gr * D + nt * 16 + cl] = pack1_bf16(acc[nt][rg]);
            }
    }
}

// ================= final aggregation (layer 2, no relu) =================

__global__ void agg_final(const float* __restrict__ Ys, const uint32_t* __restrict__ Yn2,
                          const int* __restrict__ csr, const int* __restrict__ startv,
                          const int* __restrict__ deg, float* __restrict__ out) {
    const int wave = threadIdx.x >> 6;
    const int lane = threadIdx.x & 63;
    const int v = blockIdx.x * 4 + wave;
    const int s = startv[v];
    const int dg = deg[v];
    const int* cp = csr + s;
    const int li = (lane < 48) ? lane : 0;

    float sx[8], sy[8];
#pragma unroll
    for (int i = 0; i < 8; ++i) { sx[i] = 0.f; sy[i] = 0.f; }
    int e = 0;
    for (; e + 7 < dg; e += 8) {
#pragma unroll
        for (int i = 0; i < 8; ++i) {
            uint32_t wv = Yn2[(size_t)cp[e + i] * 48 + li];
            sx[i] += bf_lo(wv); sy[i] += bf_hi(wv);
        }
    }
    for (; e < dg; ++e) {
        uint32_t wv = Yn2[(size_t)cp[e] * 48 + li];
        sx[0] += bf_lo(wv); sy[0] += bf_hi(wv);
    }
    float ax = ((sx[0] + sx[1]) + (sx[2] + sx[3])) + ((sx[4] + sx[5]) + (sx[6] + sx[7]));
    float ay = ((sy[0] + sy[1]) + (sy[2] + sy[3])) + ((sy[4] + sy[5]) + (sy[6] + sy[7]));
    const float inv = 1.f / (float)(dg > 0 ? dg : 1);
    if (lane < 48) {
        const size_t o = (size_t)v * D + 2 * lane;
        float2 ysv = *(const float2*)(Ys + o);
        out[o] = ysv.x + ax * inv;
        out[o + 1] = ysv.y + ay * inv;
    }
}

// ================= launch =================

extern "C" void kernel_launch(void* const* d_in, const int* in_sizes, int n_in,
                              void* d_out, int out_size, void* d_ws, size_t ws_size,
                              hipStream_t stream) {
    const float* x   = (const float*)d_in[0];
    const int*   src = (const int*)d_in[1];
    const int*   dst = (const int*)d_in[2];
    const float* Ws1 = (const float*)d_in[3];
    const float* Wn1 = (const float*)d_in[4];
    const float* b1  = (const float*)d_in[5];
    const float* Ws2 = (const float*)d_in[6];
    const float* Wn2 = (const float*)d_in[7];
    const float* b2  = (const float*)d_in[8];
    float* out = (float*)d_out;

    char* w = (char*)d_ws;
    int* deg        = (int*)w; w += (size_t)NN * sizeof(int);
    int* startv     = (int*)w; w += (size_t)NN * sizeof(int);
    int* bucketCnt  = (int*)w; w += NBUCK * sizeof(int);
    int* bucketBase = (int*)w; w += NBUCK * sizeof(int);
    int* bucketCur  = (int*)w; w += NBUCK * sizeof(int);
    int* csr        = (int*)w; w += (size_t)NE * sizeof(int);
    w = (char*)(((uintptr_t)w + 255) & ~(uintptr_t)255);
    unsigned short* ys1 = (unsigned short*)w; w += (size_t)NN * D * sizeof(unsigned short);
    unsigned short* yn1 = (unsigned short*)w; w += (size_t)NN * D * sizeof(unsigned short);
    float*          ys2 = (float*)w;          w += (size_t)NN * D * sizeof(float);
    unsigned short* yn2 = (unsigned short*)w; w += (size_t)NN * D * sizeof(unsigned short);
    uint32_t* bfg1 = (uint32_t*)w; w += 36 * 64 * 4 * sizeof(uint32_t);
    uint32_t* bfg2 = (uint32_t*)w; w += 36 * 64 * 4 * sizeof(uint32_t);

    // pairBuf aliases ys2: dead after csr_build, ys2 first written by fused_aggx.
    uint2* pairBuf = (uint2*)ys2;   // 6.4 MB <= 19.2 MB

    // CSR build
    hipMemsetAsync(bucketCnt, 0, NBUCK * sizeof(int), stream);
    bucket_hist<<<256, 256, 0, stream>>>(dst, bucketCnt);
    bucket_scan<<<1, NBUCK, 0, stream>>>(bucketCnt, bucketBase, bucketCur);
    bin_edges<<<NTILE, 512, 0, stream>>>(dst, src, bucketCur, pairBuf);
    csr_build<<<NBU, 256, 0, stream>>>(pairBuf, bucketBase, bucketCnt, deg, startv, csr);

    // weights
    repack_both<<<18, 256, 0, stream>>>(Ws1, Wn1, Ws2, Wn2, bfg1, bfg2);

    const int xgrid = (NN + 63) / 64;

    // layer 1 transform (f32 in, bf16 out)
    xform1_mfma<<<xgrid, 256, 0, stream>>>(x, bfg1, b1, ys1, yn1);

    // layer-1 aggregation fused with layer-2 transform
    fused_aggx<<<xgrid, 512, 0, stream>>>(ys1, (const uint32_t*)yn1, csr, startv, deg,
                                          bfg2, b2, ys2, yn2);

    // final aggregation
    agg_final<<<NN / 4, 256, 0, stream>>>(ys2, (const uint32_t*)yn2, csr, startv, deg, out);
}

// Round 9
// 110.448 us; speedup vs baseline: 6.0860x; 1.2451x over previous
//
#include <hip/hip_runtime.h>
#include <cstdint>
#include <cstddef>

#define NN 50000
#define NE 800000
#define D 96

#define NBUCK 512
#define BSH 7                       // bucket = dst >> 7 (128 nodes per bucket)
#define NBU ((NN + 127) >> 7)       // 391 used buckets
#define TILE 8192                   // edges per bin_edges block
#define NTILE ((NE + TILE - 1) / TILE)   // 98
#define MAXB 5120                   // max edges per bucket (avg 2048)

#define AGB 32                      // nodes per agg block
#define AGW 1024                    // staged csr window (32*16 avg=512; +23 sigma)

typedef __attribute__((ext_vector_type(8))) short bf16x8;
typedef __attribute__((ext_vector_type(4))) float f32x4;

// ================= CSR build: two-level LDS counting sort =================

__global__ void bucket_hist(const int* __restrict__ dst, int* __restrict__ bucketCnt) {
    __shared__ int h[NBUCK];
    for (int i = threadIdx.x; i < NBUCK; i += 256) h[i] = 0;
    __syncthreads();
    const int stride = gridDim.x * 256 * 4;
    for (int i = (blockIdx.x * 256 + (int)threadIdx.x) * 4; i < NE; i += stride) {
        int4 d4 = *(const int4*)(dst + i);   // NE % 4 == 0
        atomicAdd(&h[d4.x >> BSH], 1);
        atomicAdd(&h[d4.y >> BSH], 1);
        atomicAdd(&h[d4.z >> BSH], 1);
        atomicAdd(&h[d4.w >> BSH], 1);
    }
    __syncthreads();
    for (int i = threadIdx.x; i < NBUCK; i += 256)
        if (h[i]) atomicAdd(&bucketCnt[i], h[i]);
}

__global__ void bucket_scan(const int* __restrict__ bucketCnt, int* __restrict__ bucketBase,
                            int* __restrict__ bucketCur) {
    __shared__ int sm[NBUCK];
    const int t = threadIdx.x;      // 512 threads
    const int v = bucketCnt[t];
    sm[t] = v;
    __syncthreads();
    for (int s = 1; s < NBUCK; s <<= 1) {
        int u = (t >= s) ? sm[t - s] : 0;
        __syncthreads();
        sm[t] += u;
        __syncthreads();
    }
    const int excl = sm[t] - v;
    bucketBase[t] = excl;
    bucketCur[t] = excl;
}

__launch_bounds__(512)
__global__ void bin_edges(const int* __restrict__ dst, const int* __restrict__ src,
                          int* __restrict__ bucketCur, uint2* __restrict__ pairBuf) {
    __shared__ int hist[NBUCK];
    __shared__ int segStart[NBUCK];
    __shared__ int lcur[NBUCK];
    __shared__ int segBase[NBUCK];
    __shared__ uint2 lpair[TILE];   // 64 KB
    const int t = threadIdx.x;
    const int e0 = blockIdx.x * TILE;
    const int cnt = (NE - e0 < TILE) ? (NE - e0) : TILE;

    for (int i = t; i < NBUCK; i += 512) hist[i] = 0;
    __syncthreads();

    for (int i = t * 4; i < cnt; i += 512 * 4) {
        if (i + 3 < cnt) {
            int4 d4 = *(const int4*)(dst + e0 + i);
            atomicAdd(&hist[d4.x >> BSH], 1);
            atomicAdd(&hist[d4.y >> BSH], 1);
            atomicAdd(&hist[d4.z >> BSH], 1);
            atomicAdd(&hist[d4.w >> BSH], 1);
        } else {
            for (int k = i; k < cnt; ++k) atomicAdd(&hist[dst[e0 + k] >> BSH], 1);
        }
    }
    __syncthreads();

    {
        const int v = hist[t];
        segStart[t] = v;
        __syncthreads();
        for (int s = 1; s < NBUCK; s <<= 1) {
            int u = (t >= s) ? segStart[t - s] : 0;
            __syncthreads();
            segStart[t] += u;
            __syncthreads();
        }
        int excl = segStart[t] - v;
        __syncthreads();
        segStart[t] = excl;
        lcur[t] = excl;
    }
    __syncthreads();

    for (int i = t * 4; i < cnt; i += 512 * 4) {
        if (i + 3 < cnt) {
            int4 d4 = *(const int4*)(dst + e0 + i);
            int4 s4 = *(const int4*)(src + e0 + i);
            int p0 = atomicAdd(&lcur[d4.x >> BSH], 1); lpair[p0] = make_uint2(d4.x, s4.x);
            int p1 = atomicAdd(&lcur[d4.y >> BSH], 1); lpair[p1] = make_uint2(d4.y, s4.y);
            int p2 = atomicAdd(&lcur[d4.z >> BSH], 1); lpair[p2] = make_uint2(d4.z, s4.z);
            int p3 = atomicAdd(&lcur[d4.w >> BSH], 1); lpair[p3] = make_uint2(d4.w, s4.w);
        } else {
            for (int k = i; k < cnt; ++k) {
                int d = dst[e0 + k], s = src[e0 + k];
                int p = atomicAdd(&lcur[d >> BSH], 1);
                lpair[p] = make_uint2(d, s);
            }
        }
    }
    __syncthreads();

    {
        int c = hist[t];
        segBase[t] = c ? atomicAdd(&bucketCur[t], c) : 0;
    }
    __syncthreads();

    for (int k = t; k < cnt; k += 512) {
        uint2 p = lpair[k];
        int b = (int)p.x >> BSH;
        pairBuf[(size_t)segBase[b] + (k - segStart[b])] = p;
    }
}

__global__ void csr_build(const uint2* __restrict__ pairBuf, const int* __restrict__ bucketBase,
                          const int* __restrict__ bucketCnt, int* __restrict__ startv,
                          int* __restrict__ csr) {
    __shared__ int h[128], ls[128], cur[128];
    __shared__ int lsrc[MAXB];
    const int b = blockIdx.x;
    const int t = threadIdx.x;   // 256
    const int lo = bucketBase[b];
    int cnt = bucketCnt[b];
    if (cnt > MAXB) cnt = MAXB;
    const int node0 = b << BSH;

    if (t < 128) h[t] = 0;
    __syncthreads();
    for (int k = t; k < cnt; k += 256)
        atomicAdd(&h[(int)pairBuf[lo + k].x - node0], 1);
    __syncthreads();
    if (t < 128) ls[t] = h[t];
    __syncthreads();
    for (int s = 1; s < 128; s <<= 1) {
        int u = (t >= s && t < 128) ? ls[t - s] : 0;
        __syncthreads();
        if (t < 128) ls[t] += u;
        __syncthreads();
    }
    if (t < 128) {
        int excl = ls[t] - h[t];
        cur[t] = excl;
        int node = node0 + t;
        if (node < NN) startv[node] = lo + excl;
    }
    __syncthreads();
    for (int k = t; k < cnt; k += 256) {
        uint2 p = pairBuf[lo + k];
        int pos = atomicAdd(&cur[(int)p.x - node0], 1);
        lsrc[pos] = (int)p.y;
    }
    __syncthreads();
    for (int k = t; k < cnt; k += 256) csr[lo + k] = lsrc[k];
}

// ================= bf16 helpers (RTNE) =================

__device__ inline uint32_t pack2_bf16(float a, float b) {
    uint32_t ua = __float_as_uint(a), ub = __float_as_uint(b);
    ua = (ua + 0x7fffu + ((ua >> 16) & 1u)) >> 16;
    ub = (ub + 0x7fffu + ((ub >> 16) & 1u)) >> 16;
    return ua | (ub << 16);
}

__device__ inline unsigned short pack1_bf16(float a) {
    uint32_t ua = __float_as_uint(a);
    return (unsigned short)((ua + 0x7fffu + ((ua >> 16) & 1u)) >> 16);
}

__device__ inline float bf_lo(uint32_t w) { return __uint_as_float(w << 16); }
__device__ inline float bf_hi(uint32_t w) { return __uint_as_float(w & 0xffff0000u); }

// ================= weight repack (both layers) into MFMA B-fragment order =================

__global__ void repack_both(const float* __restrict__ Ws1, const float* __restrict__ Wn1,
                            const float* __restrict__ Ws2, const float* __restrict__ Wn2,
                            uint32_t* __restrict__ bfg1, uint32_t* __restrict__ bfg2) {
    int t = blockIdx.x * 256 + threadIdx.x;
    if (t >= 4608) return;
    const int layer = (t >= 2304);
    int tt = t - layer * 2304;
    const int isWn = (tt >= 1152);
    const float* __restrict__ W = layer ? (isWn ? Wn2 : Ws2) : (isWn ? Wn1 : Ws1);
    uint32_t* __restrict__ Bfg = layer ? bfg2 : bfg1;
    tt = isWn ? tt - 1152 : tt;
    int s = tt / 384;
    int r = tt - s * 384;
    int nt6 = r >> 6;
    int l = r & 63;
    int col = nt6 * 16 + (l & 15);
    int k0 = 32 * s + 8 * (l >> 4);
    float v[8];
#pragma unroll
    for (int j = 0; j < 8; ++j) v[j] = W[(k0 + j) * D + col];
    uint4 o;
    o.x = pack2_bf16(v[0], v[1]);
    o.y = pack2_bf16(v[2], v[3]);
    o.z = pack2_bf16(v[4], v[5]);
    o.w = pack2_bf16(v[6], v[7]);
    int nt = nt6 + (isWn ? 6 : 0);
    int slot = (s * 12 + nt) * 64 + l;
    *(uint4*)(Bfg + (size_t)slot * 4) = o;
}

// ================= layer-1 transform: x f32 in, Ys1/Yn1 bf16 out =================

__launch_bounds__(256, 2)
__global__ void xform1_mfma(const float* __restrict__ X,
                            const uint32_t* __restrict__ Bfg,
                            const float* __restrict__ Bias,
                            unsigned short* __restrict__ Ys,
                            unsigned short* __restrict__ Yn) {
    __shared__ __align__(16) uint32_t Af[3072];
    const int tid = threadIdx.x;
    const int row0 = blockIdx.x * 64;

#pragma unroll
    for (int it = 0; it < 6; ++it) {
        int flat = (it * 256 + tid) * 4;
        int r = flat / 96, k = flat - (flat / 96) * 96;
        int gr = row0 + r;
        if (gr >= NN) gr = NN - 1;
        float4 xv = *(const float4*)(X + (size_t)gr * D + k);
        int wq = r >> 4, s = k >> 5;
        int lq = ((k >> 3) & 3) * 16 + (r & 15);
        int base = ((wq * 3 + s) * 64 + lq) * 4 + ((k & 7) >> 1);
        Af[base] = pack2_bf16(xv.x, xv.y);
        Af[base + 1] = pack2_bf16(xv.z, xv.w);
    }
    __syncthreads();

    const int w = tid >> 6, l = tid & 63;
    const int cl = l & 15;

    bf16x8 a0 = *(const bf16x8*)&Af[((w * 3 + 0) * 64 + l) * 4];
    bf16x8 a1 = *(const bf16x8*)&Af[((w * 3 + 1) * 64 + l) * 4];
    bf16x8 a2 = *(const bf16x8*)&Af[((w * 3 + 2) * 64 + l) * 4];

    f32x4 acc[12];
#pragma unroll
    for (int nt = 0; nt < 6; ++nt) {
        float bv = Bias[nt * 16 + cl];
        acc[nt] = (f32x4){bv, bv, bv, bv};
    }
#pragma unroll
    for (int nt = 6; nt < 12; ++nt) acc[nt] = (f32x4){0.f, 0.f, 0.f, 0.f};

#pragma unroll
    for (int nt = 0; nt < 12; ++nt) {
        bf16x8 b0 = *(const bf16x8*)(Bfg + ((size_t)((0 * 12 + nt) * 64 + l)) * 4);
        bf16x8 b1 = *(const bf16x8*)(Bfg + ((size_t)((1 * 12 + nt) * 64 + l)) * 4);
        bf16x8 b2 = *(const bf16x8*)(Bfg + ((size_t)((2 * 12 + nt) * 64 + l)) * 4);
        acc[nt] = __builtin_amdgcn_mfma_f32_16x16x32_bf16(a0, b0, acc[nt], 0, 0, 0);
        acc[nt] = __builtin_amdgcn_mfma_f32_16x16x32_bf16(a1, b1, acc[nt], 0, 0, 0);
        acc[nt] = __builtin_amdgcn_mfma_f32_16x16x32_bf16(a2, b2, acc[nt], 0, 0, 0);
    }

    const int grb = row0 + w * 16 + (l >> 4) * 4;
#pragma unroll
    for (int nt = 0; nt < 6; ++nt)
#pragma unroll
        for (int rg = 0; rg < 4; ++rg) {
            int gr = grb + rg;
            if (gr < NN) Ys[(size_t)gr * D + nt * 16 + cl] = pack1_bf16(acc[nt][rg]);
        }
#pragma unroll
    for (int nt = 6; nt < 12; ++nt)
#pragma unroll
        for (int rg = 0; rg < 4; ++rg) {
            int gr = grb + rg;
            if (gr < NN) Yn[(size_t)gr * D + (nt - 6) * 16 + cl] = pack1_bf16(acc[nt][rg]);
        }
}

// ================= gather core (8/4/1-deep, indices from LDS or global) =================

#define GATHER_BODY(TBL, GET)                                              \
    {                                                                      \
        int e = 0;                                                         \
        for (; e + 7 < dg; e += 8) {                                       \
            _Pragma("unroll")                                              \
            for (int i = 0; i < 8; ++i) {                                  \
                uint32_t wv = TBL[(size_t)(GET(e + i)) * 48 + li];         \
                sx[i] += bf_lo(wv); sy[i] += bf_hi(wv);                    \
            }                                                              \
        }                                                                  \
        if (e + 3 < dg) {                                                  \
            _Pragma("unroll")                                              \
            for (int i = 0; i < 4; ++i) {                                  \
                uint32_t wv = TBL[(size_t)(GET(e + i)) * 48 + li];         \
                sx[i] += bf_lo(wv); sy[i] += bf_hi(wv);                    \
            }                                                              \
            e += 4;                                                        \
        }                                                                  \
        for (; e < dg; ++e) {                                              \
            uint32_t wv = TBL[(size_t)(GET(e)) * 48 + li];                 \
            sx[0] += bf_lo(wv); sy[0] += bf_hi(wv);                        \
        }                                                                  \
    }

// ================= fused layer-1 aggregation + layer-2 transform =================
// Block = 32 nodes, 4 waves. Phase A: wave w aggregates nodes w*8..w*8+7.
// Phase B: wave w = stripe (w>>1) x half (w&1): MFMA h @ W2 -> Ys2 bf16 / Yn2 bf16.

__launch_bounds__(256, 4)
__global__ void fused_aggx(const unsigned short* __restrict__ Ys1,
                           const uint32_t* __restrict__ Yn1,
                           const int* __restrict__ csr, const int* __restrict__ startv,
                           const uint32_t* __restrict__ Bfg2, const float* __restrict__ Bias2,
                           unsigned short* __restrict__ Ys2, unsigned short* __restrict__ Yn2) {
    __shared__ __align__(16) uint32_t H[AGB][52];
    __shared__ int lcsr[AGW];
    __shared__ int lsv[AGB + 1];
    const int tid = threadIdx.x;
    const int w = tid >> 6, l = tid & 63;
    const int row0 = blockIdx.x * AGB;
    const int li = (l < 48) ? l : 0;

    if (tid <= AGB) {
        int r = row0 + tid;
        lsv[tid] = (r < NN) ? startv[r] : NE;
    }
    __syncthreads();
    const int e_lo = lsv[0];
    const int wcnt = lsv[AGB] - e_lo;
    const int staged = wcnt < AGW ? wcnt : AGW;
    for (int k = tid; k < staged; k += 256) lcsr[k] = csr[e_lo + k];
    __syncthreads();

    // -------- Phase A --------
    for (int j = 0; j < 8; ++j) {
        const int vl = w * 8 + j;
        const int v = row0 + vl;
        uint32_t hpair = 0;
        if (v < NN) {
            const int sloc = lsv[vl] - e_lo;
            const int dg = lsv[vl + 1] - lsv[vl];
            float sx[8], sy[8];
#pragma unroll
            for (int i = 0; i < 8; ++i) { sx[i] = 0.f; sy[i] = 0.f; }
            if (sloc + dg <= staged) {
#define GET_L(E) lcsr[sloc + (E)]
                GATHER_BODY(Yn1, GET_L)
#undef GET_L
            } else {
                const int* cp = csr + e_lo + sloc;
#define GET_G(E) cp[E]
                GATHER_BODY(Yn1, GET_G)
#undef GET_G
            }
            float ax = ((sx[0] + sx[1]) + (sx[2] + sx[3])) + ((sx[4] + sx[5]) + (sx[6] + sx[7]));
            float ay = ((sy[0] + sy[1]) + (sy[2] + sy[3])) + ((sy[4] + sy[5]) + (sy[6] + sy[7]));
            const float inv = 1.f / (float)(dg > 0 ? dg : 1);
            uint32_t ysp = *(const uint32_t*)(Ys1 + (size_t)v * 96 + 2 * li);
            float r0 = fmaxf(bf_lo(ysp) + ax * inv, 0.f);
            float r1 = fmaxf(bf_hi(ysp) + ay * inv, 0.f);
            hpair = pack2_bf16(r0, r1);
        }
        if (l < 48) H[vl][l] = hpair;
    }
    __syncthreads();

    // -------- Phase B --------
    const int stripe = w >> 1;
    const int hf = w & 1;
    const int cl = l & 15;
    const int kq = l >> 4;

    bf16x8 a0 = *(const bf16x8*)&H[stripe * 16 + cl][0 + 4 * kq];
    bf16x8 a1 = *(const bf16x8*)&H[stripe * 16 + cl][16 + 4 * kq];
    bf16x8 a2 = *(const bf16x8*)&H[stripe * 16 + cl][32 + 4 * kq];

    f32x4 acc[6];
#pragma unroll
    for (int nt = 0; nt < 6; ++nt) {
        float bv = hf ? 0.f : Bias2[nt * 16 + cl];
        acc[nt] = (f32x4){bv, bv, bv, bv};
    }
#pragma unroll
    for (int nt = 0; nt < 6; ++nt) {
        int ntg = hf * 6 + nt;
        bf16x8 b0 = *(const bf16x8*)(Bfg2 + ((size_t)((0 * 12 + ntg) * 64 + l)) * 4);
        bf16x8 b1 = *(const bf16x8*)(Bfg2 + ((size_t)((1 * 12 + ntg) * 64 + l)) * 4);
        bf16x8 b2 = *(const bf16x8*)(Bfg2 + ((size_t)((2 * 12 + ntg) * 64 + l)) * 4);
        acc[nt] = __builtin_amdgcn_mfma_f32_16x16x32_bf16(a0, b0, acc[nt], 0, 0, 0);
        acc[nt] = __builtin_amdgcn_mfma_f32_16x16x32_bf16(a1, b1, acc[nt], 0, 0, 0);
        acc[nt] = __builtin_amdgcn_mfma_f32_16x16x32_bf16(a2, b2, acc[nt], 0, 0, 0);
    }

    const int grb = row0 + stripe * 16 + kq * 4;
    if (hf == 0) {
#pragma unroll
        for (int nt = 0; nt < 6; ++nt)
#pragma unroll
            for (int rg = 0; rg < 4; ++rg) {
                int gr = grb + rg;
                if (gr < NN) Ys2[(size_t)gr * D + nt * 16 + cl] = pack1_bf16(acc[nt][rg]);
            }
    } else {
#pragma unroll
        for (int nt = 0; nt < 6; ++nt)
#pragma unroll
            for (int rg = 0; rg < 4; ++rg) {
                int gr = grb + rg;
                if (gr < NN) Yn2[(size_t)gr * D + nt * 16 + cl] = pack1_bf16(acc[nt][rg]);
            }
    }
}

// ================= final aggregation (layer 2, no relu) =================

__launch_bounds__(256, 4)
__global__ void agg_final(const unsigned short* __restrict__ Ys2b,
                          const uint32_t* __restrict__ Yn2,
                          const int* __restrict__ csr, const int* __restrict__ startv,
                          float* __restrict__ out) {
    __shared__ int lcsr[AGW];
    __shared__ int lsv[AGB + 1];
    const int tid = threadIdx.x;
    const int w = tid >> 6, l = tid & 63;
    const int row0 = blockIdx.x * AGB;
    const int li = (l < 48) ? l : 0;

    if (tid <= AGB) {
        int r = row0 + tid;
        lsv[tid] = (r < NN) ? startv[r] : NE;
    }
    __syncthreads();
    const int e_lo = lsv[0];
    const int wcnt = lsv[AGB] - e_lo;
    const int staged = wcnt < AGW ? wcnt : AGW;
    for (int k = tid; k < staged; k += 256) lcsr[k] = csr[e_lo + k];
    __syncthreads();

    for (int j = 0; j < 8; ++j) {
        const int vl = w * 8 + j;
        const int v = row0 + vl;
        if (v >= NN) continue;
        const int sloc = lsv[vl] - e_lo;
        const int dg = lsv[vl + 1] - lsv[vl];
        float sx[8], sy[8];
#pragma unroll
        for (int i = 0; i < 8; ++i) { sx[i] = 0.f; sy[i] = 0.f; }
        if (sloc + dg <= staged) {
#define GET_L(E) lcsr[sloc + (E)]
            GATHER_BODY(Yn2, GET_L)
#undef GET_L
        } else {
            const int* cp = csr + e_lo + sloc;
#define GET_G(E) cp[E]
            GATHER_BODY(Yn2, GET_G)
#undef GET_G
        }
        float ax = ((sx[0] + sx[1]) + (sx[2] + sx[3])) + ((sx[4] + sx[5]) + (sx[6] + sx[7]));
        float ay = ((sy[0] + sy[1]) + (sy[2] + sy[3])) + ((sy[4] + sy[5]) + (sy[6] + sy[7]));
        const float inv = 1.f / (float)(dg > 0 ? dg : 1);
        if (l < 48) {
            const size_t o = (size_t)v * D + 2 * li;
            uint32_t ysp = *(const uint32_t*)(Ys2b + (size_t)v * 96 + 2 * li);
            out[o] = bf_lo(ysp) + ax * inv;
            out[o + 1] = bf_hi(ysp) + ay * inv;
        }
    }
}

// ================= launch =================

extern "C" void kernel_launch(void* const* d_in, const int* in_sizes, int n_in,
                              void* d_out, int out_size, void* d_ws, size_t ws_size,
                              hipStream_t stream) {
    const float* x   = (const float*)d_in[0];
    const int*   src = (const int*)d_in[1];
    const int*   dst = (const int*)d_in[2];
    const float* Ws1 = (const float*)d_in[3];
    const float* Wn1 = (const float*)d_in[4];
    const float* b1  = (const float*)d_in[5];
    const float* Ws2 = (const float*)d_in[6];
    const float* Wn2 = (const float*)d_in[7];
    const float* b2  = (const float*)d_in[8];
    float* out = (float*)d_out;

    char* w = (char*)d_ws;
    int* startv     = (int*)w; w += (size_t)NN * sizeof(int);
    int* bucketCnt  = (int*)w; w += NBUCK * sizeof(int);
    int* bucketBase = (int*)w; w += NBUCK * sizeof(int);
    int* bucketCur  = (int*)w; w += NBUCK * sizeof(int);
    int* csr        = (int*)w; w += (size_t)NE * sizeof(int);
    w = (char*)(((uintptr_t)w + 255) & ~(uintptr_t)255);
    unsigned short* ys1 = (unsigned short*)w; w += (size_t)NN * D * sizeof(unsigned short);
    unsigned short* yn1 = (unsigned short*)w; w += (size_t)NN * D * sizeof(unsigned short);
    unsigned short* ys2 = (unsigned short*)w; w += (size_t)NN * D * sizeof(unsigned short);
    unsigned short* yn2 = (unsigned short*)w; w += (size_t)NN * D * sizeof(unsigned short);
    uint32_t* bfg1 = (uint32_t*)w; w += 36 * 64 * 4 * sizeof(uint32_t);
    uint32_t* bfg2 = (uint32_t*)w; w += 36 * 64 * 4 * sizeof(uint32_t);

    // pairBuf aliases ys1+ys2 region? No: alias ys1..yn1 block (19.2 MB >= 6.4 MB),
    // both first written after csr_build completes.
    uint2* pairBuf = (uint2*)ys1;

    // CSR build
    hipMemsetAsync(bucketCnt, 0, NBUCK * sizeof(int), stream);
    bucket_hist<<<256, 256, 0, stream>>>(dst, bucketCnt);
    bucket_scan<<<1, NBUCK, 0, stream>>>(bucketCnt, bucketBase, bucketCur);
    bin_edges<<<NTILE, 512, 0, stream>>>(dst, src, bucketCur, pairBuf);
    csr_build<<<NBU, 256, 0, stream>>>(pairBuf, bucketBase, bucketCnt, startv, csr);

    // weights
    repack_both<<<18, 256, 0, stream>>>(Ws1, Wn1, Ws2, Wn2, bfg1, bfg2);

    // layer 1 transform (f32 in, bf16 out)
    xform1_mfma<<<(NN + 63) / 64, 256, 0, stream>>>(x, bfg1, b1, ys1, yn1);

    const int agrid = (NN + AGB - 1) / AGB;

    // layer-1 aggregation fused with layer-2 transform
    fused_aggx<<<agrid, 256, 0, stream>>>(ys1, (const uint32_t*)yn1, csr, startv,
                                          bfg2, b2, ys2, yn2);

    // final aggregation
    agg_final<<<agrid, 256, 0, stream>>>(ys2, (const uint32_t*)yn2, csr, startv, out);
}